// Round 6
// baseline (121.039 us; speedup 1.0000x reference)
//
#include <hip/hip_runtime.h>

#define TT 768
#define KD 512
#define NC 1024
#define RLN2_2 2.8853900817779268f   // 2/ln(2)

typedef short short8 __attribute__((ext_vector_type(8)));
typedef float f32x4  __attribute__((ext_vector_type(4)));

__device__ __forceinline__ float fast_exp2(float x) {
#if __has_builtin(__builtin_amdgcn_exp2f)
    return __builtin_amdgcn_exp2f(x);
#else
    return exp2f(x);
#endif
}
__device__ __forceinline__ float fast_rcp(float x) {
#if __has_builtin(__builtin_amdgcn_rcpf)
    return __builtin_amdgcn_rcpf(x);
#else
    return 1.0f / x;
#endif
}
__device__ __forceinline__ float fast_tanh(float x) {
    float e = fast_exp2(x * RLN2_2);
    return fmaf(-2.0f, fast_rcp(e + 1.0f), 1.0f);
}
__device__ __forceinline__ ushort f2bf(float f) {   // RNE f32->bf16
    uint u = __float_as_uint(f);
    u += 0x7fff + ((u >> 16) & 1);
    return (ushort)(u >> 16);
}

// ---------------------------------------------------------------------------
// Prep: x->bf16; foh/fom -> [c][k] bf16; hid2 -> [n][k] bf16 (transposes)
// ---------------------------------------------------------------------------
__global__ __launch_bounds__(256) void k_prep(
    const float* __restrict__ x, const float* __restrict__ foh,
    const float* __restrict__ fom, const float* __restrict__ hid2,
    ushort* __restrict__ xb, ushort* __restrict__ b1t, ushort* __restrict__ h2t)
{
    const int b = blockIdx.x, t = threadIdx.x;
    if (b < 96) {
        int base = b * 4096 + t * 16;
        #pragma unroll
        for (int q = 0; q < 4; ++q) {
            float4 v = *(const float4*)&x[base + q * 4];
            ushort4 o; o.x = f2bf(v.x); o.y = f2bf(v.y); o.z = f2bf(v.z); o.w = f2bf(v.w);
            *(ushort4*)&xb[base + q * 4] = o;
        }
        return;
    }
    __shared__ float tile[64][65];
    const float* src; ushort* dst; int R, C, r0, c0;
    if (b < 160)      { int bb = b - 96;  src = foh;  dst = b1t;             R = 512;  C = 512; r0 = (bb >> 3) * 64; c0 = (bb & 7) * 64; }
    else if (b < 224) { int bb = b - 160; src = fom;  dst = b1t + 512 * 512; R = 512;  C = 512; r0 = (bb >> 3) * 64; c0 = (bb & 7) * 64; }
    else              { int bb = b - 224; src = hid2; dst = h2t;             R = 1024; C = 512; r0 = (bb >> 3) * 64; c0 = (bb & 7) * 64; }
    const int ty = t >> 4, tx = t & 15;
    #pragma unroll
    for (int q = 0; q < 4; ++q) {
        float4 v = *(const float4*)&src[(r0 + ty + q * 16) * C + c0 + tx * 4];
        tile[ty + q * 16][tx * 4 + 0] = v.x;
        tile[ty + q * 16][tx * 4 + 1] = v.y;
        tile[ty + q * 16][tx * 4 + 2] = v.z;
        tile[ty + q * 16][tx * 4 + 3] = v.w;
    }
    __syncthreads();
    #pragma unroll
    for (int q = 0; q < 4; ++q) {
        int cl = ty + q * 16;
        ushort4 o;
        o.x = f2bf(tile[tx * 4 + 0][cl]);
        o.y = f2bf(tile[tx * 4 + 1][cl]);
        o.z = f2bf(tile[tx * 4 + 2][cl]);
        o.w = f2bf(tile[tx * 4 + 3][cl]);
        *(ushort4*)&dst[(c0 + cl) * R + r0 + tx * 4] = o;
    }
}

// ---------------------------------------------------------------------------
// GEMM1 (MFMA bf16): act = tanh(xb @ b1t^T + catBias), bf16 out
// ---------------------------------------------------------------------------
__global__ __launch_bounds__(256) void k_gemm1(
    const ushort* __restrict__ xb, const ushort* __restrict__ b1t,
    const float* __restrict__ catBias, ushort* __restrict__ act)
{
    const int t = threadIdx.x;
    const int wave = t >> 6, lane = t & 63;
    const int wr = wave >> 1, wc = wave & 1;
    const int n0 = blockIdx.x * 64 + wc * 32;
    const int m0 = blockIdx.y * 64 + wr * 32;
    const int lrow = lane & 15, lk = (lane >> 4) * 8;

    const ushort* pa0 = &xb[(m0 + lrow) * KD + lk];
    const ushort* pa1 = pa0 + 16 * KD;
    const ushort* pb0 = &b1t[(n0 + lrow) * KD + lk];
    const ushort* pb1 = pb0 + 16 * KD;

    f32x4 acc[2][2] = {};
    #pragma unroll 4
    for (int k0 = 0; k0 < KD; k0 += 32) {
        short8 a0 = *(const short8*)(pa0 + k0);
        short8 a1 = *(const short8*)(pa1 + k0);
        short8 b0 = *(const short8*)(pb0 + k0);
        short8 b1 = *(const short8*)(pb1 + k0);
        acc[0][0] = __builtin_amdgcn_mfma_f32_16x16x32_bf16(a0, b0, acc[0][0], 0, 0, 0);
        acc[0][1] = __builtin_amdgcn_mfma_f32_16x16x32_bf16(a0, b1, acc[0][1], 0, 0, 0);
        acc[1][0] = __builtin_amdgcn_mfma_f32_16x16x32_bf16(a1, b0, acc[1][0], 0, 0, 0);
        acc[1][1] = __builtin_amdgcn_mfma_f32_16x16x32_bf16(a1, b1, acc[1][1], 0, 0, 0);
    }
    const int crow = (lane >> 4) * 4, ccol = lane & 15;
    #pragma unroll
    for (int nf = 0; nf < 2; ++nf) {
        int col = n0 + nf * 16 + ccol;
        float cb = catBias[col];
        #pragma unroll
        for (int mf = 0; mf < 2; ++mf) {
            #pragma unroll
            for (int r = 0; r < 4; ++r) {
                int row = m0 + mf * 16 + crow + r;
                act[row * NC + col] = f2bf(fast_tanh(acc[mf][nf][r] + cb));
            }
        }
    }
}

// ---------------------------------------------------------------------------
// GEMM2 (MFMA bf16) + exp epilogue -> pw = EA | EM (f32)
// ---------------------------------------------------------------------------
__global__ __launch_bounds__(256) void k_gemm2(
    const ushort* __restrict__ act, const ushort* __restrict__ h2t,
    const float* __restrict__ hid2Bias, float* __restrict__ pw)
{
    const int t = threadIdx.x;
    const int wave = t >> 6, lane = t & 63;
    const int wr = wave >> 1, wc = wave & 1;
    const int n0 = blockIdx.x * 64 + wc * 32;
    const int m0 = blockIdx.y * 64 + wr * 32;
    const bool top = (blockIdx.x < 8);
    const int koff = top ? 0 : 512;
    const int nc0  = top ? n0 : n0 - 512;
    const int lrow = lane & 15, lk = (lane >> 4) * 8;

    const ushort* pa0 = &act[(m0 + lrow) * NC + koff + lk];
    const ushort* pa1 = pa0 + 16 * NC;
    const ushort* pb0 = &h2t[(nc0 + lrow) * NC + koff + lk];
    const ushort* pb1 = pb0 + 16 * NC;

    f32x4 acc[2][2] = {};
    #pragma unroll 4
    for (int k0 = 0; k0 < KD; k0 += 32) {
        short8 a0 = *(const short8*)(pa0 + k0);
        short8 a1 = *(const short8*)(pa1 + k0);
        short8 b0 = *(const short8*)(pb0 + k0);
        short8 b1 = *(const short8*)(pb1 + k0);
        acc[0][0] = __builtin_amdgcn_mfma_f32_16x16x32_bf16(a0, b0, acc[0][0], 0, 0, 0);
        acc[0][1] = __builtin_amdgcn_mfma_f32_16x16x32_bf16(a0, b1, acc[0][1], 0, 0, 0);
        acc[1][0] = __builtin_amdgcn_mfma_f32_16x16x32_bf16(a1, b0, acc[1][0], 0, 0, 0);
        acc[1][1] = __builtin_amdgcn_mfma_f32_16x16x32_bf16(a1, b1, acc[1][1], 0, 0, 0);
    }
    const int crow = (lane >> 4) * 4, ccol = lane & 15;
    #pragma unroll
    for (int nf = 0; nf < 2; ++nf) {
        int col = n0 + nf * 16 + ccol;
        float hb = top ? hid2Bias[col] : 0.0f;
        #pragma unroll
        for (int mf = 0; mf < 2; ++mf) {
            #pragma unroll
            for (int r = 0; r < 4; ++r) {
                int row = m0 + mf * 16 + crow + r;
                pw[row * NC + col] = fast_exp2(RLN2_2 * (acc[mf][nf][r] + hb));
            }
        }
    }
}

// ---------------------------------------------------------------------------
// Pairwise: out[i][j] = (outBias + sum w) - 2*sum_h w[h]/(1 + EA[i,h]*EM[j,h])
// 16x16 tile per 1-wave block, 2x2 micro, grid 2304 (9 waves/CU, XCD-swizzled).
// NO LDS staging of EA/EM -- pw is 3 MB, L2-resident; operands are loaded
// directly from global (8-way shared addresses coalesce; L1/L2 serve them).
// Only w lives in LDS (uniform broadcast b128 reads). Batched rcp: 1 per quad.
// ---------------------------------------------------------------------------
__global__ __launch_bounds__(64) void k_pair(
    const float* __restrict__ pw, const float* __restrict__ w,
    const float* __restrict__ outBias, float* __restrict__ out)
{
    __shared__ float wl[512];
    const int t   = threadIdx.x;
    const int bid = blockIdx.x;
    const int sw  = (bid & 7) * 288 + (bid >> 3);   // XCD swizzle (8 | 2304)
    const int it = sw / 48, jt = sw % 48;
    const int i0 = it * 16, j0 = jt * 16;
    const int ti = t >> 3, tj = t & 7;

    // w -> LDS once; wsum via butterfly (single wave, no barrier needed)
    float4 wa = *(const float4*)&w[t * 8];
    float4 wb = *(const float4*)&w[t * 8 + 4];
    *(float4*)&wl[t * 8]     = wa;
    *(float4*)&wl[t * 8 + 4] = wb;
    float lsum = (wa.x + wa.y) + (wa.z + wa.w) + (wb.x + wb.y) + (wb.z + wb.w);
    #pragma unroll
    for (int d = 1; d < 64; d <<= 1) lsum += __shfl_xor(lsum, d, 64);

    const float* e0p = &pw[(i0 + 2 * ti) * NC];
    const float* e1p = e0p + NC;
    const float* f0p = &pw[(j0 + 2 * tj) * NC + 512];
    const float* f1p = f0p + NC;

    float acc00 = 0.f, acc01 = 0.f, acc10 = 0.f, acc11 = 0.f;

    #pragma unroll 8
    for (int hq = 0; hq < 128; ++hq) {              // 4 h per iteration
        float4 e0 = *(const float4*)(e0p + hq * 4);
        float4 e1 = *(const float4*)(e1p + hq * 4);
        float4 f0 = *(const float4*)(f0p + hq * 4);
        float4 f1 = *(const float4*)(f1p + hq * 4);
        float4 w4 = *(const float4*)&wl[hq * 4];    // uniform -> LDS broadcast
        #define QUAD(H)                                                      \
        {                                                                    \
            float d00 = fmaf(e0.H, f0.H, 1.f), d01 = fmaf(e0.H, f1.H, 1.f);  \
            float d10 = fmaf(e1.H, f0.H, 1.f), d11 = fmaf(e1.H, f1.H, 1.f);  \
            float P0 = d00 * d01, P1 = d10 * d11;                            \
            float R  = fast_rcp(P0 * P1);                                    \
            float rw = R * w4.H;                                             \
            float rw0 = rw * P1, rw1 = rw * P0;                              \
            acc00 = fmaf(rw0, d01, acc00);                                   \
            acc01 = fmaf(rw0, d00, acc01);                                   \
            acc10 = fmaf(rw1, d11, acc10);                                   \
            acc11 = fmaf(rw1, d10, acc11);                                   \
        }
        QUAD(x) QUAD(y) QUAD(z) QUAD(w)
        #undef QUAD
    }

    const float base = lsum + outBias[0];
    const int gi = i0 + 2 * ti, gj = j0 + 2 * tj;
    float2 r0, r1;
    r0.x = fmaf(-2.f, acc00, base);
    r0.y = fmaf(-2.f, acc01, base);
    r1.x = fmaf(-2.f, acc10, base);
    r1.y = fmaf(-2.f, acc11, base);
    *(float2*)&out[gi * TT + gj]       = r0;
    *(float2*)&out[(gi + 1) * TT + gj] = r1;
}

extern "C" void kernel_launch(void* const* d_in, const int* in_sizes, int n_in,
                              void* d_out, int out_size, void* d_ws, size_t ws_size,
                              hipStream_t stream) {
    const float* x        = (const float*)d_in[0];
    const float* foh      = (const float*)d_in[1];
    const float* fom      = (const float*)d_in[2];
    const float* catBias  = (const float*)d_in[3];
    const float* hid2     = (const float*)d_in[4];
    const float* hid2Bias = (const float*)d_in[5];
    const float* outLayer = (const float*)d_in[6];
    const float* outBias  = (const float*)d_in[7];
    float* out = (float*)d_out;

    char* wsb = (char*)d_ws;
    float*  pw  = (float*)(wsb);                        // 768*1024*4
    ushort* act = (ushort*)(wsb + 3145728);             // 768*1024*2
    ushort* xb  = (ushort*)(wsb + 4718592);             // 768*512*2
    ushort* b1t = (ushort*)(wsb + 5505024);             // 1024*512*2
    ushort* h2t = (ushort*)(wsb + 6553600);             // 512*1024*2

    k_prep <<<dim3(352),    256, 0, stream>>>(x, foh, fom, hid2, xb, b1t, h2t);
    k_gemm1<<<dim3(16, 12), 256, 0, stream>>>(xb, b1t, catBias, act);
    k_gemm2<<<dim3(16, 12), 256, 0, stream>>>(act, h2t, hid2Bias, pw);
    k_pair <<<dim3(2304),    64, 0, stream>>>(pw, outLayer, outBias, out);
}

// Round 7
// 96.255 us; speedup vs baseline: 1.2575x; 1.2575x over previous
//
#include <hip/hip_runtime.h>

#define TT 768
#define KD 512
#define NC 1024
#define RLN2_2 2.8853900817779268f   // 2/ln(2)

typedef short short8 __attribute__((ext_vector_type(8)));
typedef float f32x4  __attribute__((ext_vector_type(4)));

__device__ __forceinline__ float fast_exp2(float x) {
#if __has_builtin(__builtin_amdgcn_exp2f)
    return __builtin_amdgcn_exp2f(x);
#else
    return exp2f(x);
#endif
}
__device__ __forceinline__ float fast_rcp(float x) {
#if __has_builtin(__builtin_amdgcn_rcpf)
    return __builtin_amdgcn_rcpf(x);
#else
    return 1.0f / x;
#endif
}
__device__ __forceinline__ float fast_tanh(float x) {
    float e = fast_exp2(x * RLN2_2);
    return fmaf(-2.0f, fast_rcp(e + 1.0f), 1.0f);
}
__device__ __forceinline__ ushort f2bf(float f) {   // RNE f32->bf16
    uint u = __float_as_uint(f);
    u += 0x7fff + ((u >> 16) & 1);
    return (ushort)(u >> 16);
}

// ---------------------------------------------------------------------------
// Prep: x->bf16; foh/fom -> [c][k] bf16; hid2 -> [n][k] bf16 (transposes)
// ---------------------------------------------------------------------------
__global__ __launch_bounds__(256) void k_prep(
    const float* __restrict__ x, const float* __restrict__ foh,
    const float* __restrict__ fom, const float* __restrict__ hid2,
    ushort* __restrict__ xb, ushort* __restrict__ b1t, ushort* __restrict__ h2t)
{
    const int b = blockIdx.x, t = threadIdx.x;
    if (b < 96) {
        int base = b * 4096 + t * 16;
        #pragma unroll
        for (int q = 0; q < 4; ++q) {
            float4 v = *(const float4*)&x[base + q * 4];
            ushort4 o; o.x = f2bf(v.x); o.y = f2bf(v.y); o.z = f2bf(v.z); o.w = f2bf(v.w);
            *(ushort4*)&xb[base + q * 4] = o;
        }
        return;
    }
    __shared__ float tile[64][65];
    const float* src; ushort* dst; int R, C, r0, c0;
    if (b < 160)      { int bb = b - 96;  src = foh;  dst = b1t;             R = 512;  C = 512; r0 = (bb >> 3) * 64; c0 = (bb & 7) * 64; }
    else if (b < 224) { int bb = b - 160; src = fom;  dst = b1t + 512 * 512; R = 512;  C = 512; r0 = (bb >> 3) * 64; c0 = (bb & 7) * 64; }
    else              { int bb = b - 224; src = hid2; dst = h2t;             R = 1024; C = 512; r0 = (bb >> 3) * 64; c0 = (bb & 7) * 64; }
    const int ty = t >> 4, tx = t & 15;
    #pragma unroll
    for (int q = 0; q < 4; ++q) {
        float4 v = *(const float4*)&src[(r0 + ty + q * 16) * C + c0 + tx * 4];
        tile[ty + q * 16][tx * 4 + 0] = v.x;
        tile[ty + q * 16][tx * 4 + 1] = v.y;
        tile[ty + q * 16][tx * 4 + 2] = v.z;
        tile[ty + q * 16][tx * 4 + 3] = v.w;
    }
    __syncthreads();
    #pragma unroll
    for (int q = 0; q < 4; ++q) {
        int cl = ty + q * 16;
        ushort4 o;
        o.x = f2bf(tile[tx * 4 + 0][cl]);
        o.y = f2bf(tile[tx * 4 + 1][cl]);
        o.z = f2bf(tile[tx * 4 + 2][cl]);
        o.w = f2bf(tile[tx * 4 + 3][cl]);
        *(ushort4*)&dst[(c0 + cl) * R + r0 + tx * 4] = o;
    }
}

// ---------------------------------------------------------------------------
// GEMM1 (MFMA bf16): act = tanh(xb @ b1t^T + catBias), bf16 out
// ---------------------------------------------------------------------------
__global__ __launch_bounds__(256) void k_gemm1(
    const ushort* __restrict__ xb, const ushort* __restrict__ b1t,
    const float* __restrict__ catBias, ushort* __restrict__ act)
{
    const int t = threadIdx.x;
    const int wave = t >> 6, lane = t & 63;
    const int wr = wave >> 1, wc = wave & 1;
    const int n0 = blockIdx.x * 64 + wc * 32;
    const int m0 = blockIdx.y * 64 + wr * 32;
    const int lrow = lane & 15, lk = (lane >> 4) * 8;

    const ushort* pa0 = &xb[(m0 + lrow) * KD + lk];
    const ushort* pa1 = pa0 + 16 * KD;
    const ushort* pb0 = &b1t[(n0 + lrow) * KD + lk];
    const ushort* pb1 = pb0 + 16 * KD;

    f32x4 acc[2][2] = {};
    #pragma unroll 4
    for (int k0 = 0; k0 < KD; k0 += 32) {
        short8 a0 = *(const short8*)(pa0 + k0);
        short8 a1 = *(const short8*)(pa1 + k0);
        short8 b0 = *(const short8*)(pb0 + k0);
        short8 b1 = *(const short8*)(pb1 + k0);
        acc[0][0] = __builtin_amdgcn_mfma_f32_16x16x32_bf16(a0, b0, acc[0][0], 0, 0, 0);
        acc[0][1] = __builtin_amdgcn_mfma_f32_16x16x32_bf16(a0, b1, acc[0][1], 0, 0, 0);
        acc[1][0] = __builtin_amdgcn_mfma_f32_16x16x32_bf16(a1, b0, acc[1][0], 0, 0, 0);
        acc[1][1] = __builtin_amdgcn_mfma_f32_16x16x32_bf16(a1, b1, acc[1][1], 0, 0, 0);
    }
    const int crow = (lane >> 4) * 4, ccol = lane & 15;
    #pragma unroll
    for (int nf = 0; nf < 2; ++nf) {
        int col = n0 + nf * 16 + ccol;
        float cb = catBias[col];
        #pragma unroll
        for (int mf = 0; mf < 2; ++mf) {
            #pragma unroll
            for (int r = 0; r < 4; ++r) {
                int row = m0 + mf * 16 + crow + r;
                act[row * NC + col] = f2bf(fast_tanh(acc[mf][nf][r] + cb));
            }
        }
    }
}

// ---------------------------------------------------------------------------
// GEMM2 (MFMA bf16) + exp epilogue -> pw = EA | EM (f32)
// ---------------------------------------------------------------------------
__global__ __launch_bounds__(256) void k_gemm2(
    const ushort* __restrict__ act, const ushort* __restrict__ h2t,
    const float* __restrict__ hid2Bias, float* __restrict__ pw)
{
    const int t = threadIdx.x;
    const int wave = t >> 6, lane = t & 63;
    const int wr = wave >> 1, wc = wave & 1;
    const int n0 = blockIdx.x * 64 + wc * 32;
    const int m0 = blockIdx.y * 64 + wr * 32;
    const bool top = (blockIdx.x < 8);
    const int koff = top ? 0 : 512;
    const int nc0  = top ? n0 : n0 - 512;
    const int lrow = lane & 15, lk = (lane >> 4) * 8;

    const ushort* pa0 = &act[(m0 + lrow) * NC + koff + lk];
    const ushort* pa1 = pa0 + 16 * NC;
    const ushort* pb0 = &h2t[(nc0 + lrow) * NC + koff + lk];
    const ushort* pb1 = pb0 + 16 * NC;

    f32x4 acc[2][2] = {};
    #pragma unroll 4
    for (int k0 = 0; k0 < KD; k0 += 32) {
        short8 a0 = *(const short8*)(pa0 + k0);
        short8 a1 = *(const short8*)(pa1 + k0);
        short8 b0 = *(const short8*)(pb0 + k0);
        short8 b1 = *(const short8*)(pb1 + k0);
        acc[0][0] = __builtin_amdgcn_mfma_f32_16x16x32_bf16(a0, b0, acc[0][0], 0, 0, 0);
        acc[0][1] = __builtin_amdgcn_mfma_f32_16x16x32_bf16(a0, b1, acc[0][1], 0, 0, 0);
        acc[1][0] = __builtin_amdgcn_mfma_f32_16x16x32_bf16(a1, b0, acc[1][0], 0, 0, 0);
        acc[1][1] = __builtin_amdgcn_mfma_f32_16x16x32_bf16(a1, b1, acc[1][1], 0, 0, 0);
    }
    const int crow = (lane >> 4) * 4, ccol = lane & 15;
    #pragma unroll
    for (int nf = 0; nf < 2; ++nf) {
        int col = n0 + nf * 16 + ccol;
        float hb = top ? hid2Bias[col] : 0.0f;
        #pragma unroll
        for (int mf = 0; mf < 2; ++mf) {
            #pragma unroll
            for (int r = 0; r < 4; ++r) {
                int row = m0 + mf * 16 + crow + r;
                pw[row * NC + col] = fast_exp2(RLN2_2 * (acc[mf][nf][r] + hb));
            }
        }
    }
}

// ---------------------------------------------------------------------------
// Pairwise: out[i][j] = (outBias + sum w) - 2*sum_h w[h]/(1 + EA[i,h]*EM[j,h])
// r3 structure (16x16 tile / 1-wave block / LDS-staged / grid 2304, XCD-swz)
// + batched rcp (1 per 2x2 quad) + 16 independent accumulators (one 2x2 set
// per h-slot) so the 4 quads per iteration share no dependency chain.
// ---------------------------------------------------------------------------
__global__ __launch_bounds__(64) void k_pair(
    const float* __restrict__ pw, const float* __restrict__ w,
    const float* __restrict__ outBias, float* __restrict__ out)
{
    __shared__ float Ea[16][68];
    __shared__ float Em[16][68];
    __shared__ float wl[512];

    const int t   = threadIdx.x;
    const int bid = blockIdx.x;
    const int sw  = (bid & 7) * 288 + (bid >> 3);   // XCD swizzle (8 | 2304)
    const int it = sw / 48, jt = sw % 48;
    const int i0 = it * 16, j0 = jt * 16;
    const int ti = t >> 3, tj = t & 7;

    // w -> LDS + wsum butterfly (single wave, no barrier needed)
    float4 wa = *(const float4*)&w[t * 8];
    float4 wb = *(const float4*)&w[t * 8 + 4];
    *(float4*)&wl[t * 8]     = wa;
    *(float4*)&wl[t * 8 + 4] = wb;
    float lsum = (wa.x + wa.y) + (wa.z + wa.w) + (wb.x + wb.y) + (wb.z + wb.w);
    #pragma unroll
    for (int d = 1; d < 64; d <<= 1) lsum += __shfl_xor(lsum, d, 64);

    // staging geometry: rows 4q + (t>>4), cols (t&15)*4 of a 16x64 chunk
    const int sr = t >> 4;
    const int sc = (t & 15) * 4;
    const float* srcA = &pw[(i0 + sr) * NC + sc];
    const float* srcM = &pw[(j0 + sr) * NC + 512 + sc];

    float4 fa[4], fm[4];
    #pragma unroll
    for (int q = 0; q < 4; ++q) fa[q] = *(const float4*)(srcA + q * 4 * NC);
    #pragma unroll
    for (int q = 0; q < 4; ++q) fm[q] = *(const float4*)(srcM + q * 4 * NC);

    // 16 accumulators: [h-slot 0..3][i2][j2], all independent
    float a00[4] = {}, a01[4] = {}, a10[4] = {}, a11[4] = {};

    #pragma unroll 1
    for (int c = 0; c < 8; ++c) {
        const int hh = c * 64;
        __syncthreads();                              // WAR: prev reads done
        #pragma unroll
        for (int q = 0; q < 4; ++q) *(float4*)&Ea[4 * q + sr][sc] = fa[q];
        #pragma unroll
        for (int q = 0; q < 4; ++q) *(float4*)&Em[4 * q + sr][sc] = fm[q];
        __syncthreads();                              // RAW: writes visible
        if (c < 7) {
            #pragma unroll
            for (int q = 0; q < 4; ++q) fa[q] = *(const float4*)(srcA + hh + 64 + q * 4 * NC);
            #pragma unroll
            for (int q = 0; q < 4; ++q) fm[q] = *(const float4*)(srcM + hh + 64 + q * 4 * NC);
        }
        #pragma unroll
        for (int hq = 0; hq < 16; ++hq) {
            float4 e0 = *(const float4*)&Ea[2 * ti    ][hq * 4];
            float4 e1 = *(const float4*)&Ea[2 * ti + 1][hq * 4];
            float4 f0 = *(const float4*)&Em[2 * tj    ][hq * 4];
            float4 f1 = *(const float4*)&Em[2 * tj + 1][hq * 4];
            float4 w4 = *(const float4*)&wl[hh + hq * 4];   // uniform -> broadcast
            #define QUAD(H, S)                                                   \
            {                                                                    \
                float d00 = fmaf(e0.H, f0.H, 1.f), d01 = fmaf(e0.H, f1.H, 1.f);  \
                float d10 = fmaf(e1.H, f0.H, 1.f), d11 = fmaf(e1.H, f1.H, 1.f);  \
                float P0 = d00 * d01, P1 = d10 * d11;                            \
                float R  = fast_rcp(P0 * P1);                                    \
                float rw = R * w4.H;                                             \
                float rw0 = rw * P1, rw1 = rw * P0;                              \
                a00[S] = fmaf(rw0, d01, a00[S]);                                 \
                a01[S] = fmaf(rw0, d00, a01[S]);                                 \
                a10[S] = fmaf(rw1, d11, a10[S]);                                 \
                a11[S] = fmaf(rw1, d10, a11[S]);                                 \
            }
            QUAD(x, 0) QUAD(y, 1) QUAD(z, 2) QUAD(w, 3)
            #undef QUAD
        }
    }

    const float base = lsum + outBias[0];
    const float s00 = (a00[0] + a00[1]) + (a00[2] + a00[3]);
    const float s01 = (a01[0] + a01[1]) + (a01[2] + a01[3]);
    const float s10 = (a10[0] + a10[1]) + (a10[2] + a10[3]);
    const float s11 = (a11[0] + a11[1]) + (a11[2] + a11[3]);
    const int gi = i0 + 2 * ti, gj = j0 + 2 * tj;
    float2 r0, r1;
    r0.x = fmaf(-2.f, s00, base);
    r0.y = fmaf(-2.f, s01, base);
    r1.x = fmaf(-2.f, s10, base);
    r1.y = fmaf(-2.f, s11, base);
    *(float2*)&out[gi * TT + gj]       = r0;
    *(float2*)&out[(gi + 1) * TT + gj] = r1;
}

extern "C" void kernel_launch(void* const* d_in, const int* in_sizes, int n_in,
                              void* d_out, int out_size, void* d_ws, size_t ws_size,
                              hipStream_t stream) {
    const float* x        = (const float*)d_in[0];
    const float* foh      = (const float*)d_in[1];
    const float* fom      = (const float*)d_in[2];
    const float* catBias  = (const float*)d_in[3];
    const float* hid2     = (const float*)d_in[4];
    const float* hid2Bias = (const float*)d_in[5];
    const float* outLayer = (const float*)d_in[6];
    const float* outBias  = (const float*)d_in[7];
    float* out = (float*)d_out;

    char* wsb = (char*)d_ws;
    float*  pw  = (float*)(wsb);                        // 768*1024*4
    ushort* act = (ushort*)(wsb + 3145728);             // 768*1024*2
    ushort* xb  = (ushort*)(wsb + 4718592);             // 768*512*2
    ushort* b1t = (ushort*)(wsb + 5505024);             // 1024*512*2
    ushort* h2t = (ushort*)(wsb + 6553600);             // 512*1024*2

    k_prep <<<dim3(352),    256, 0, stream>>>(x, foh, fom, hid2, xb, b1t, h2t);
    k_gemm1<<<dim3(16, 12), 256, 0, stream>>>(xb, b1t, catBias, act);
    k_gemm2<<<dim3(16, 12), 256, 0, stream>>>(act, h2t, hid2Bias, pw);
    k_pair <<<dim3(2304),    64, 0, stream>>>(pw, outLayer, outBias, out);
}

// Round 8
// 82.795 us; speedup vs baseline: 1.4619x; 1.1626x over previous
//
#include <hip/hip_runtime.h>

#define TT 768
#define KD 512
#define NC 1024
#define RLN2_2 2.8853900817779268f   // 2/ln(2)

typedef short short8 __attribute__((ext_vector_type(8)));
typedef float f32x4  __attribute__((ext_vector_type(4)));

__device__ __forceinline__ float fast_exp2(float x) {
#if __has_builtin(__builtin_amdgcn_exp2f)
    return __builtin_amdgcn_exp2f(x);
#else
    return exp2f(x);
#endif
}
__device__ __forceinline__ float fast_rcp(float x) {
#if __has_builtin(__builtin_amdgcn_rcpf)
    return __builtin_amdgcn_rcpf(x);
#else
    return 1.0f / x;
#endif
}
__device__ __forceinline__ float fast_tanh(float x) {
    float e = fast_exp2(x * RLN2_2);
    return fmaf(-2.0f, fast_rcp(e + 1.0f), 1.0f);
}
__device__ __forceinline__ ushort f2bf(float f) {   // RNE f32->bf16
    uint u = __float_as_uint(f);
    u += 0x7fff + ((u >> 16) & 1);
    return (ushort)(u >> 16);
}

// ---------------------------------------------------------------------------
// Prep: x->bf16; foh/fom -> [c][k] bf16; hid2 -> [n][k] bf16 (transposes)
// ---------------------------------------------------------------------------
__global__ __launch_bounds__(256) void k_prep(
    const float* __restrict__ x, const float* __restrict__ foh,
    const float* __restrict__ fom, const float* __restrict__ hid2,
    ushort* __restrict__ xb, ushort* __restrict__ b1t, ushort* __restrict__ h2t)
{
    const int b = blockIdx.x, t = threadIdx.x;
    if (b < 96) {
        int base = b * 4096 + t * 16;
        #pragma unroll
        for (int q = 0; q < 4; ++q) {
            float4 v = *(const float4*)&x[base + q * 4];
            ushort4 o; o.x = f2bf(v.x); o.y = f2bf(v.y); o.z = f2bf(v.z); o.w = f2bf(v.w);
            *(ushort4*)&xb[base + q * 4] = o;
        }
        return;
    }
    __shared__ float tile[64][65];
    const float* src; ushort* dst; int R, C, r0, c0;
    if (b < 160)      { int bb = b - 96;  src = foh;  dst = b1t;             R = 512;  C = 512; r0 = (bb >> 3) * 64; c0 = (bb & 7) * 64; }
    else if (b < 224) { int bb = b - 160; src = fom;  dst = b1t + 512 * 512; R = 512;  C = 512; r0 = (bb >> 3) * 64; c0 = (bb & 7) * 64; }
    else              { int bb = b - 224; src = hid2; dst = h2t;             R = 1024; C = 512; r0 = (bb >> 3) * 64; c0 = (bb & 7) * 64; }
    const int ty = t >> 4, tx = t & 15;
    #pragma unroll
    for (int q = 0; q < 4; ++q) {
        float4 v = *(const float4*)&src[(r0 + ty + q * 16) * C + c0 + tx * 4];
        tile[ty + q * 16][tx * 4 + 0] = v.x;
        tile[ty + q * 16][tx * 4 + 1] = v.y;
        tile[ty + q * 16][tx * 4 + 2] = v.z;
        tile[ty + q * 16][tx * 4 + 3] = v.w;
    }
    __syncthreads();
    #pragma unroll
    for (int q = 0; q < 4; ++q) {
        int cl = ty + q * 16;
        ushort4 o;
        o.x = f2bf(tile[tx * 4 + 0][cl]);
        o.y = f2bf(tile[tx * 4 + 1][cl]);
        o.z = f2bf(tile[tx * 4 + 2][cl]);
        o.w = f2bf(tile[tx * 4 + 3][cl]);
        *(ushort4*)&dst[(c0 + cl) * R + r0 + tx * 4] = o;
    }
}

// ---------------------------------------------------------------------------
// GEMM1 (MFMA bf16): act = tanh(xb @ b1t^T + catBias), bf16 out
// ---------------------------------------------------------------------------
__global__ __launch_bounds__(256) void k_gemm1(
    const ushort* __restrict__ xb, const ushort* __restrict__ b1t,
    const float* __restrict__ catBias, ushort* __restrict__ act)
{
    const int t = threadIdx.x;
    const int wave = t >> 6, lane = t & 63;
    const int wr = wave >> 1, wc = wave & 1;
    const int n0 = blockIdx.x * 64 + wc * 32;
    const int m0 = blockIdx.y * 64 + wr * 32;
    const int lrow = lane & 15, lk = (lane >> 4) * 8;

    const ushort* pa0 = &xb[(m0 + lrow) * KD + lk];
    const ushort* pa1 = pa0 + 16 * KD;
    const ushort* pb0 = &b1t[(n0 + lrow) * KD + lk];
    const ushort* pb1 = pb0 + 16 * KD;

    f32x4 acc[2][2] = {};
    #pragma unroll 4
    for (int k0 = 0; k0 < KD; k0 += 32) {
        short8 a0 = *(const short8*)(pa0 + k0);
        short8 a1 = *(const short8*)(pa1 + k0);
        short8 b0 = *(const short8*)(pb0 + k0);
        short8 b1 = *(const short8*)(pb1 + k0);
        acc[0][0] = __builtin_amdgcn_mfma_f32_16x16x32_bf16(a0, b0, acc[0][0], 0, 0, 0);
        acc[0][1] = __builtin_amdgcn_mfma_f32_16x16x32_bf16(a0, b1, acc[0][1], 0, 0, 0);
        acc[1][0] = __builtin_amdgcn_mfma_f32_16x16x32_bf16(a1, b0, acc[1][0], 0, 0, 0);
        acc[1][1] = __builtin_amdgcn_mfma_f32_16x16x32_bf16(a1, b1, acc[1][1], 0, 0, 0);
    }
    const int crow = (lane >> 4) * 4, ccol = lane & 15;
    #pragma unroll
    for (int nf = 0; nf < 2; ++nf) {
        int col = n0 + nf * 16 + ccol;
        float cb = catBias[col];
        #pragma unroll
        for (int mf = 0; mf < 2; ++mf) {
            #pragma unroll
            for (int r = 0; r < 4; ++r) {
                int row = m0 + mf * 16 + crow + r;
                act[row * NC + col] = f2bf(fast_tanh(acc[mf][nf][r] + cb));
            }
        }
    }
}

// ---------------------------------------------------------------------------
// GEMM2 (MFMA bf16) + exp epilogue -> pw = EA | EM (f32)
// ---------------------------------------------------------------------------
__global__ __launch_bounds__(256) void k_gemm2(
    const ushort* __restrict__ act, const ushort* __restrict__ h2t,
    const float* __restrict__ hid2Bias, float* __restrict__ pw)
{
    const int t = threadIdx.x;
    const int wave = t >> 6, lane = t & 63;
    const int wr = wave >> 1, wc = wave & 1;
    const int n0 = blockIdx.x * 64 + wc * 32;
    const int m0 = blockIdx.y * 64 + wr * 32;
    const bool top = (blockIdx.x < 8);
    const int koff = top ? 0 : 512;
    const int nc0  = top ? n0 : n0 - 512;
    const int lrow = lane & 15, lk = (lane >> 4) * 8;

    const ushort* pa0 = &act[(m0 + lrow) * NC + koff + lk];
    const ushort* pa1 = pa0 + 16 * NC;
    const ushort* pb0 = &h2t[(nc0 + lrow) * NC + koff + lk];
    const ushort* pb1 = pb0 + 16 * NC;

    f32x4 acc[2][2] = {};
    #pragma unroll 4
    for (int k0 = 0; k0 < KD; k0 += 32) {
        short8 a0 = *(const short8*)(pa0 + k0);
        short8 a1 = *(const short8*)(pa1 + k0);
        short8 b0 = *(const short8*)(pb0 + k0);
        short8 b1 = *(const short8*)(pb1 + k0);
        acc[0][0] = __builtin_amdgcn_mfma_f32_16x16x32_bf16(a0, b0, acc[0][0], 0, 0, 0);
        acc[0][1] = __builtin_amdgcn_mfma_f32_16x16x32_bf16(a0, b1, acc[0][1], 0, 0, 0);
        acc[1][0] = __builtin_amdgcn_mfma_f32_16x16x32_bf16(a1, b0, acc[1][0], 0, 0, 0);
        acc[1][1] = __builtin_amdgcn_mfma_f32_16x16x32_bf16(a1, b1, acc[1][1], 0, 0, 0);
    }
    const int crow = (lane >> 4) * 4, ccol = lane & 15;
    #pragma unroll
    for (int nf = 0; nf < 2; ++nf) {
        int col = n0 + nf * 16 + ccol;
        float hb = top ? hid2Bias[col] : 0.0f;
        #pragma unroll
        for (int mf = 0; mf < 2; ++mf) {
            #pragma unroll
            for (int r = 0; r < 4; ++r) {
                int row = m0 + mf * 16 + crow + r;
                pw[row * NC + col] = fast_exp2(RLN2_2 * (acc[mf][nf][r] + hb));
            }
        }
    }
}

// ---------------------------------------------------------------------------
// Pairwise: out[i][j] = (outBias + sum w) - 2*sum_h w[h]/(1 + EA[i,h]*EM[j,h])
// 16x16 tile per block, but TWO waves per block splitting the i-rows
// (wave 0 -> rows 0..7, wave 1 -> rows 8..15) sharing one Ea/Em staging.
// Grid 2304 blocks x 2 waves = 4608 waves = 18/CU (was 9). LDS 10752 B.
// Lane = 8i x 8j, micro 1i x 2j; batched rcp over (2h x 2j) quads;
// 8 independent accumulators. No combine step (waves own disjoint rows).
// ---------------------------------------------------------------------------
__global__ __launch_bounds__(128) void k_pair(
    const float* __restrict__ pw, const float* __restrict__ w,
    const float* __restrict__ outBias, float* __restrict__ out)
{
    __shared__ float Ea[16][68];
    __shared__ float Em[16][68];
    __shared__ float wl[512];

    const int t    = threadIdx.x;
    const int wv   = t >> 6, lane = t & 63;
    const int bid  = blockIdx.x;
    const int sw   = (bid & 7) * 288 + (bid >> 3);   // XCD swizzle (8 | 2304)
    const int it = sw / 48, jt = sw % 48;
    const int i0 = it * 16, j0 = jt * 16;

    // w -> LDS (128 threads x 4 floats); wsum per-wave via global + butterfly
    *(float4*)&wl[t * 4] = *(const float4*)&w[t * 4];
    float4 wa = *(const float4*)&w[lane * 8];
    float4 wb = *(const float4*)&w[lane * 8 + 4];
    float lsum = (wa.x + wa.y) + (wa.z + wa.w) + (wb.x + wb.y) + (wb.z + wb.w);
    #pragma unroll
    for (int d = 1; d < 64; d <<= 1) lsum += __shfl_xor(lsum, d, 64);

    // staging geometry: 128 threads cover 16 rows x 64 cols, 8 floats each
    const int sr = t >> 3;              // 0..15
    const int sc = (t & 7) * 8;         // 0..56
    const float* srcA = &pw[(i0 + sr) * NC + sc];
    const float* srcM = &pw[(j0 + sr) * NC + 512 + sc];

    // compute geometry: wave wv owns rows wv*8 .. wv*8+7
    const int erow = wv * 8 + (lane >> 3);
    const int jr   = 2 * (lane & 7);

    float4 fa0 = *(const float4*)(srcA);
    float4 fa1 = *(const float4*)(srcA + 4);
    float4 fm0 = *(const float4*)(srcM);
    float4 fm1 = *(const float4*)(srcM + 4);

    // 8 independent accumulators: [j-sub][quad-slot 0..3]
    float accA0[2] = {}, accA1[2] = {};   // h-even part, slots per quad
    float accB0[2] = {}, accB1[2] = {};   // h-odd part

    #pragma unroll 1
    for (int c = 0; c < 8; ++c) {
        const int hh = c * 64;
        __syncthreads();                              // WAR: prev reads done
        *(float4*)&Ea[sr][sc]     = fa0;
        *(float4*)&Ea[sr][sc + 4] = fa1;
        *(float4*)&Em[sr][sc]     = fm0;
        *(float4*)&Em[sr][sc + 4] = fm1;
        __syncthreads();                              // RAW: writes visible
        if (c < 7) {
            fa0 = *(const float4*)(srcA + hh + 64);
            fa1 = *(const float4*)(srcA + hh + 68);
            fm0 = *(const float4*)(srcM + hh + 64);
            fm1 = *(const float4*)(srcM + hh + 68);
        }
        #pragma unroll
        for (int hq = 0; hq < 16; ++hq) {
            float4 e4  = *(const float4*)&Ea[erow  ][hq * 4];
            float4 f04 = *(const float4*)&Em[jr    ][hq * 4];
            float4 f14 = *(const float4*)&Em[jr + 1][hq * 4];
            float4 w4  = *(const float4*)&wl[hh + hq * 4];   // uniform broadcast
            #define QUAD2(H1, H2, S)                                             \
            {                                                                    \
                float d00 = fmaf(e4.H1, f04.H1, 1.f);                            \
                float d01 = fmaf(e4.H1, f14.H1, 1.f);                            \
                float d10 = fmaf(e4.H2, f04.H2, 1.f);                            \
                float d11 = fmaf(e4.H2, f14.H2, 1.f);                            \
                float P0 = d00 * d01, P1 = d10 * d11;                            \
                float R  = fast_rcp(P0 * P1);                                    \
                float rwa = (R * P1) * w4.H1;                                    \
                float rwb = (R * P0) * w4.H2;                                    \
                accA0[S] = fmaf(rwa, d01, accA0[S]);                             \
                accA1[S] = fmaf(rwa, d00, accA1[S]);                             \
                accB0[S] = fmaf(rwb, d11, accB0[S]);                             \
                accB1[S] = fmaf(rwb, d10, accB1[S]);                             \
            }
            QUAD2(x, y, 0)
            QUAD2(z, w, 1)
            #undef QUAD2
        }
    }

    const float base = lsum + outBias[0];
    const float s0 = (accA0[0] + accA0[1]) + (accB0[0] + accB0[1]);
    const float s1 = (accA1[0] + accA1[1]) + (accB1[0] + accB1[1]);
    const int gi = i0 + erow, gj = j0 + jr;
    float2 o;
    o.x = fmaf(-2.f, s0, base);
    o.y = fmaf(-2.f, s1, base);
    *(float2*)&out[gi * TT + gj] = o;
}

extern "C" void kernel_launch(void* const* d_in, const int* in_sizes, int n_in,
                              void* d_out, int out_size, void* d_ws, size_t ws_size,
                              hipStream_t stream) {
    const float* x        = (const float*)d_in[0];
    const float* foh      = (const float*)d_in[1];
    const float* fom      = (const float*)d_in[2];
    const float* catBias  = (const float*)d_in[3];
    const float* hid2     = (const float*)d_in[4];
    const float* hid2Bias = (const float*)d_in[5];
    const float* outLayer = (const float*)d_in[6];
    const float* outBias  = (const float*)d_in[7];
    float* out = (float*)d_out;

    char* wsb = (char*)d_ws;
    float*  pw  = (float*)(wsb);                        // 768*1024*4
    ushort* act = (ushort*)(wsb + 3145728);             // 768*1024*2
    ushort* xb  = (ushort*)(wsb + 4718592);             // 768*512*2
    ushort* b1t = (ushort*)(wsb + 5505024);             // 1024*512*2
    ushort* h2t = (ushort*)(wsb + 6553600);             // 512*1024*2

    k_prep <<<dim3(352),    256, 0, stream>>>(x, foh, fom, hid2, xb, b1t, h2t);
    k_gemm1<<<dim3(16, 12), 256, 0, stream>>>(xb, b1t, catBias, act);
    k_gemm2<<<dim3(16, 12), 256, 0, stream>>>(act, h2t, hid2Bias, pw);
    k_pair <<<dim3(2304),   128, 0, stream>>>(pw, outLayer, outBias, out);
}

// Round 9
// 79.792 us; speedup vs baseline: 1.5169x; 1.0376x over previous
//
#include <hip/hip_runtime.h>

#define TT 768
#define KD 512
#define NC 1024
#define RLN2_2 2.8853900817779268f   // 2/ln(2)

typedef short short8 __attribute__((ext_vector_type(8)));
typedef float f32x4  __attribute__((ext_vector_type(4)));

__device__ __forceinline__ float fast_exp2(float x) {
#if __has_builtin(__builtin_amdgcn_exp2f)
    return __builtin_amdgcn_exp2f(x);
#else
    return exp2f(x);
#endif
}
__device__ __forceinline__ float fast_rcp(float x) {
#if __has_builtin(__builtin_amdgcn_rcpf)
    return __builtin_amdgcn_rcpf(x);
#else
    return 1.0f / x;
#endif
}
__device__ __forceinline__ float fast_tanh(float x) {
    float e = fast_exp2(x * RLN2_2);
    return fmaf(-2.0f, fast_rcp(e + 1.0f), 1.0f);
}
__device__ __forceinline__ ushort f2bf(float f) {   // RNE f32->bf16
    uint u = __float_as_uint(f);
    u += 0x7fff + ((u >> 16) & 1);
    return (ushort)(u >> 16);
}

// ---------------------------------------------------------------------------
// Prep: x->bf16; foh/fom -> [c][k] bf16; hid2 -> [n][k] bf16 (transposes)
// ---------------------------------------------------------------------------
__global__ __launch_bounds__(256) void k_prep(
    const float* __restrict__ x, const float* __restrict__ foh,
    const float* __restrict__ fom, const float* __restrict__ hid2,
    ushort* __restrict__ xb, ushort* __restrict__ b1t, ushort* __restrict__ h2t)
{
    const int b = blockIdx.x, t = threadIdx.x;
    if (b < 96) {
        int base = b * 4096 + t * 16;
        #pragma unroll
        for (int q = 0; q < 4; ++q) {
            float4 v = *(const float4*)&x[base + q * 4];
            ushort4 o; o.x = f2bf(v.x); o.y = f2bf(v.y); o.z = f2bf(v.z); o.w = f2bf(v.w);
            *(ushort4*)&xb[base + q * 4] = o;
        }
        return;
    }
    __shared__ float tile[64][65];
    const float* src; ushort* dst; int R, C, r0, c0;
    if (b < 160)      { int bb = b - 96;  src = foh;  dst = b1t;             R = 512;  C = 512; r0 = (bb >> 3) * 64; c0 = (bb & 7) * 64; }
    else if (b < 224) { int bb = b - 160; src = fom;  dst = b1t + 512 * 512; R = 512;  C = 512; r0 = (bb >> 3) * 64; c0 = (bb & 7) * 64; }
    else              { int bb = b - 224; src = hid2; dst = h2t;             R = 1024; C = 512; r0 = (bb >> 3) * 64; c0 = (bb & 7) * 64; }
    const int ty = t >> 4, tx = t & 15;
    #pragma unroll
    for (int q = 0; q < 4; ++q) {
        float4 v = *(const float4*)&src[(r0 + ty + q * 16) * C + c0 + tx * 4];
        tile[ty + q * 16][tx * 4 + 0] = v.x;
        tile[ty + q * 16][tx * 4 + 1] = v.y;
        tile[ty + q * 16][tx * 4 + 2] = v.z;
        tile[ty + q * 16][tx * 4 + 3] = v.w;
    }
    __syncthreads();
    #pragma unroll
    for (int q = 0; q < 4; ++q) {
        int cl = ty + q * 16;
        ushort4 o;
        o.x = f2bf(tile[tx * 4 + 0][cl]);
        o.y = f2bf(tile[tx * 4 + 1][cl]);
        o.z = f2bf(tile[tx * 4 + 2][cl]);
        o.w = f2bf(tile[tx * 4 + 3][cl]);
        *(ushort4*)&dst[(c0 + cl) * R + r0 + tx * 4] = o;
    }
}

// ---------------------------------------------------------------------------
// GEMM1 (MFMA bf16): act = tanh(xb @ b1t^T + catBias), bf16 out
// 1-wave blocks, 32x32 tile (2x2 16x16x32 frags), grid 32x24 = 768 blocks
// (3 blocks/CU for latency hiding; was 192 blocks = 0.75/CU).
// ---------------------------------------------------------------------------
__global__ __launch_bounds__(64) void k_gemm1(
    const ushort* __restrict__ xb, const ushort* __restrict__ b1t,
    const float* __restrict__ catBias, ushort* __restrict__ act)
{
    const int lane = threadIdx.x;
    const int n0 = blockIdx.x * 32;
    const int m0 = blockIdx.y * 32;
    const int lrow = lane & 15, lk = (lane >> 4) * 8;

    const ushort* pa0 = &xb[(m0 + lrow) * KD + lk];
    const ushort* pa1 = pa0 + 16 * KD;
    const ushort* pb0 = &b1t[(n0 + lrow) * KD + lk];
    const ushort* pb1 = pb0 + 16 * KD;

    f32x4 acc[2][2] = {};
    #pragma unroll 4
    for (int k0 = 0; k0 < KD; k0 += 32) {
        short8 a0 = *(const short8*)(pa0 + k0);
        short8 a1 = *(const short8*)(pa1 + k0);
        short8 b0 = *(const short8*)(pb0 + k0);
        short8 b1 = *(const short8*)(pb1 + k0);
        acc[0][0] = __builtin_amdgcn_mfma_f32_16x16x32_bf16(a0, b0, acc[0][0], 0, 0, 0);
        acc[0][1] = __builtin_amdgcn_mfma_f32_16x16x32_bf16(a0, b1, acc[0][1], 0, 0, 0);
        acc[1][0] = __builtin_amdgcn_mfma_f32_16x16x32_bf16(a1, b0, acc[1][0], 0, 0, 0);
        acc[1][1] = __builtin_amdgcn_mfma_f32_16x16x32_bf16(a1, b1, acc[1][1], 0, 0, 0);
    }
    const int crow = (lane >> 4) * 4, ccol = lane & 15;
    #pragma unroll
    for (int nf = 0; nf < 2; ++nf) {
        int col = n0 + nf * 16 + ccol;
        float cb = catBias[col];
        #pragma unroll
        for (int mf = 0; mf < 2; ++mf) {
            #pragma unroll
            for (int r = 0; r < 4; ++r) {
                int row = m0 + mf * 16 + crow + r;
                act[row * NC + col] = f2bf(fast_tanh(acc[mf][nf][r] + cb));
            }
        }
    }
}

// ---------------------------------------------------------------------------
// GEMM2 (MFMA bf16) + exp epilogue -> pw = EA | EM (f32). Same tiling.
// ---------------------------------------------------------------------------
__global__ __launch_bounds__(64) void k_gemm2(
    const ushort* __restrict__ act, const ushort* __restrict__ h2t,
    const float* __restrict__ hid2Bias, float* __restrict__ pw)
{
    const int lane = threadIdx.x;
    const int n0 = blockIdx.x * 32;
    const int m0 = blockIdx.y * 32;
    const bool top = (blockIdx.x < 16);
    const int koff = top ? 0 : 512;
    const int nc0  = top ? n0 : n0 - 512;
    const int lrow = lane & 15, lk = (lane >> 4) * 8;

    const ushort* pa0 = &act[(m0 + lrow) * NC + koff + lk];
    const ushort* pa1 = pa0 + 16 * NC;
    const ushort* pb0 = &h2t[(nc0 + lrow) * NC + koff + lk];
    const ushort* pb1 = pb0 + 16 * NC;

    f32x4 acc[2][2] = {};
    #pragma unroll 4
    for (int k0 = 0; k0 < KD; k0 += 32) {
        short8 a0 = *(const short8*)(pa0 + k0);
        short8 a1 = *(const short8*)(pa1 + k0);
        short8 b0 = *(const short8*)(pb0 + k0);
        short8 b1 = *(const short8*)(pb1 + k0);
        acc[0][0] = __builtin_amdgcn_mfma_f32_16x16x32_bf16(a0, b0, acc[0][0], 0, 0, 0);
        acc[0][1] = __builtin_amdgcn_mfma_f32_16x16x32_bf16(a0, b1, acc[0][1], 0, 0, 0);
        acc[1][0] = __builtin_amdgcn_mfma_f32_16x16x32_bf16(a1, b0, acc[1][0], 0, 0, 0);
        acc[1][1] = __builtin_amdgcn_mfma_f32_16x16x32_bf16(a1, b1, acc[1][1], 0, 0, 0);
    }
    const int crow = (lane >> 4) * 4, ccol = lane & 15;
    #pragma unroll
    for (int nf = 0; nf < 2; ++nf) {
        int col = n0 + nf * 16 + ccol;
        float hb = top ? hid2Bias[col] : 0.0f;
        #pragma unroll
        for (int mf = 0; mf < 2; ++mf) {
            #pragma unroll
            for (int r = 0; r < 4; ++r) {
                int row = m0 + mf * 16 + crow + r;
                pw[row * NC + col] = fast_exp2(RLN2_2 * (acc[mf][nf][r] + hb));
            }
        }
    }
}

// ---------------------------------------------------------------------------
// Pairwise: out[i][j] = (outBias + sum w) - 2*sum_h w[h]/(1 + EA[i,h]*EM[j,h])
// 16x16 tile / 2-wave block, BARRIER-FREE: each wave stages its own private
// 8 Ea rows + private copy of all 16 Em rows (wave-internal DS ordering is
// in-order -> no __syncthreads anywhere). wl written identically by both
// waves (benign race). Grid 2304 (XCD-swz). Micro 1ix2j, batched rcp.
// ---------------------------------------------------------------------------
__global__ __launch_bounds__(128) void k_pair(
    const float* __restrict__ pw, const float* __restrict__ w,
    const float* __restrict__ outBias, float* __restrict__ out)
{
    __shared__ float Ea[2][8][68];
    __shared__ float Em[2][16][68];
    __shared__ float wl[512];

    const int t    = threadIdx.x;
    const int wv   = t >> 6, lane = t & 63;
    const int bid  = blockIdx.x;
    const int sw   = (bid & 7) * 288 + (bid >> 3);   // XCD swizzle (8 | 2304)
    const int it = sw / 48, jt = sw % 48;
    const int i0 = it * 16, j0 = jt * 16;

    // w -> LDS: both waves write ALL 512 entries (identical values, benign
    // race) so each wave's reads are ordered behind its OWN writes.
    float4 wa = *(const float4*)&w[lane * 8];
    float4 wb = *(const float4*)&w[lane * 8 + 4];
    *(float4*)&wl[lane * 8]     = wa;
    *(float4*)&wl[lane * 8 + 4] = wb;
    float lsum = (wa.x + wa.y) + (wa.z + wa.w) + (wb.x + wb.y) + (wb.z + wb.w);
    #pragma unroll
    for (int d = 1; d < 64; d <<= 1) lsum += __shfl_xor(lsum, d, 64);

    // per-wave staging geometry
    const int war = lane >> 3;          // Ea row 0..7 (own i-half)
    const int cac = (lane & 7) * 8;     // 8 floats
    const int rmr = lane >> 2;          // Em row 0..15
    const int cmc = (lane & 3) * 16;    // 16 floats
    const float* srcA = &pw[(i0 + wv * 8 + war) * NC + cac];
    const float* srcM = &pw[(j0 + rmr) * NC + 512 + cmc];

    // compute geometry
    const int erow = lane >> 3;         // row in own Ea
    const int jr   = 2 * (lane & 7);

    float4 fa0 = *(const float4*)(srcA);
    float4 fa1 = *(const float4*)(srcA + 4);
    float4 fm0 = *(const float4*)(srcM);
    float4 fm1 = *(const float4*)(srcM + 4);
    float4 fm2 = *(const float4*)(srcM + 8);
    float4 fm3 = *(const float4*)(srcM + 12);

    float accA0[2] = {}, accA1[2] = {};
    float accB0[2] = {}, accB1[2] = {};

    #pragma unroll 1
    for (int c = 0; c < 8; ++c) {
        const int hh = c * 64;
        // stage current chunk (wave-private regions; DS pipe in-order per
        // wave => prior chunk's reads complete before these writes land)
        *(float4*)&Ea[wv][war][cac]      = fa0;
        *(float4*)&Ea[wv][war][cac + 4]  = fa1;
        *(float4*)&Em[wv][rmr][cmc]      = fm0;
        *(float4*)&Em[wv][rmr][cmc + 4]  = fm1;
        *(float4*)&Em[wv][rmr][cmc + 8]  = fm2;
        *(float4*)&Em[wv][rmr][cmc + 12] = fm3;
        if (c < 7) {
            fa0 = *(const float4*)(srcA + hh + 64);
            fa1 = *(const float4*)(srcA + hh + 68);
            fm0 = *(const float4*)(srcM + hh + 64);
            fm1 = *(const float4*)(srcM + hh + 68);
            fm2 = *(const float4*)(srcM + hh + 72);
            fm3 = *(const float4*)(srcM + hh + 76);
        }
        #pragma unroll
        for (int hq = 0; hq < 16; ++hq) {
            float4 e4  = *(const float4*)&Ea[wv][erow  ][hq * 4];
            float4 f04 = *(const float4*)&Em[wv][jr    ][hq * 4];
            float4 f14 = *(const float4*)&Em[wv][jr + 1][hq * 4];
            float4 w4  = *(const float4*)&wl[hh + hq * 4];   // uniform broadcast
            #define QUAD2(H1, H2, S)                                             \
            {                                                                    \
                float d00 = fmaf(e4.H1, f04.H1, 1.f);                            \
                float d01 = fmaf(e4.H1, f14.H1, 1.f);                            \
                float d10 = fmaf(e4.H2, f04.H2, 1.f);                            \
                float d11 = fmaf(e4.H2, f14.H2, 1.f);                            \
                float P0 = d00 * d01, P1 = d10 * d11;                            \
                float R  = fast_rcp(P0 * P1);                                    \
                float rwa = (R * P1) * w4.H1;                                    \
                float rwb = (R * P0) * w4.H2;                                    \
                accA0[S] = fmaf(rwa, d01, accA0[S]);                             \
                accA1[S] = fmaf(rwa, d00, accA1[S]);                             \
                accB0[S] = fmaf(rwb, d11, accB0[S]);                             \
                accB1[S] = fmaf(rwb, d10, accB1[S]);                             \
            }
            QUAD2(x, y, 0)
            QUAD2(z, w, 1)
            #undef QUAD2
        }
    }

    const float base = lsum + outBias[0];
    const float s0 = (accA0[0] + accA0[1]) + (accB0[0] + accB0[1]);
    const float s1 = (accA1[0] + accA1[1]) + (accB1[0] + accB1[1]);
    const int gi = i0 + wv * 8 + erow, gj = j0 + jr;
    float2 o;
    o.x = fmaf(-2.f, s0, base);
    o.y = fmaf(-2.f, s1, base);
    *(float2*)&out[gi * TT + gj] = o;
}

extern "C" void kernel_launch(void* const* d_in, const int* in_sizes, int n_in,
                              void* d_out, int out_size, void* d_ws, size_t ws_size,
                              hipStream_t stream) {
    const float* x        = (const float*)d_in[0];
    const float* foh      = (const float*)d_in[1];
    const float* fom      = (const float*)d_in[2];
    const float* catBias  = (const float*)d_in[3];
    const float* hid2     = (const float*)d_in[4];
    const float* hid2Bias = (const float*)d_in[5];
    const float* outLayer = (const float*)d_in[6];
    const float* outBias  = (const float*)d_in[7];
    float* out = (float*)d_out;

    char* wsb = (char*)d_ws;
    float*  pw  = (float*)(wsb);                        // 768*1024*4
    ushort* act = (ushort*)(wsb + 3145728);             // 768*1024*2
    ushort* xb  = (ushort*)(wsb + 4718592);             // 768*512*2
    ushort* b1t = (ushort*)(wsb + 5505024);             // 1024*512*2
    ushort* h2t = (ushort*)(wsb + 6553600);             // 512*1024*2

    k_prep <<<dim3(352),    256, 0, stream>>>(x, foh, fom, hid2, xb, b1t, h2t);
    k_gemm1<<<dim3(32, 24),  64, 0, stream>>>(xb, b1t, catBias, act);
    k_gemm2<<<dim3(32, 24),  64, 0, stream>>>(act, h2t, hid2Bias, pw);
    k_pair <<<dim3(2304),   128, 0, stream>>>(pw, outLayer, outBias, out);
}

// Round 10
// 72.211 us; speedup vs baseline: 1.6762x; 1.1050x over previous
//
#include <hip/hip_runtime.h>

#define TT 768
#define KD 512
#define NC 1024
#define RLN2_2 2.8853900817779268f   // 2/ln(2)

typedef short short8 __attribute__((ext_vector_type(8)));
typedef float f32x4  __attribute__((ext_vector_type(4)));

__device__ __forceinline__ float fast_exp2(float x) {
#if __has_builtin(__builtin_amdgcn_exp2f)
    return __builtin_amdgcn_exp2f(x);
#else
    return exp2f(x);
#endif
}
__device__ __forceinline__ float fast_rcp(float x) {
#if __has_builtin(__builtin_amdgcn_rcpf)
    return __builtin_amdgcn_rcpf(x);
#else
    return 1.0f / x;
#endif
}
__device__ __forceinline__ float fast_tanh(float x) {
    float e = fast_exp2(x * RLN2_2);
    return fmaf(-2.0f, fast_rcp(e + 1.0f), 1.0f);
}
__device__ __forceinline__ ushort f2bf(float f) {   // RNE f32->bf16
    uint u = __float_as_uint(f);
    u += 0x7fff + ((u >> 16) & 1);
    return (ushort)(u >> 16);
}

// ---------------------------------------------------------------------------
// Prep: x->bf16; foh/fom -> [c][k] bf16; hid2 -> [n][k] bf16 (transposes)
// ---------------------------------------------------------------------------
__global__ __launch_bounds__(256) void k_prep(
    const float* __restrict__ x, const float* __restrict__ foh,
    const float* __restrict__ fom, const float* __restrict__ hid2,
    ushort* __restrict__ xb, ushort* __restrict__ b1t, ushort* __restrict__ h2t)
{
    const int b = blockIdx.x, t = threadIdx.x;
    if (b < 96) {
        int base = b * 4096 + t * 16;
        #pragma unroll
        for (int q = 0; q < 4; ++q) {
            float4 v = *(const float4*)&x[base + q * 4];
            ushort4 o; o.x = f2bf(v.x); o.y = f2bf(v.y); o.z = f2bf(v.z); o.w = f2bf(v.w);
            *(ushort4*)&xb[base + q * 4] = o;
        }
        return;
    }
    __shared__ float tile[64][65];
    const float* src; ushort* dst; int R, C, r0, c0;
    if (b < 160)      { int bb = b - 96;  src = foh;  dst = b1t;             R = 512;  C = 512; r0 = (bb >> 3) * 64; c0 = (bb & 7) * 64; }
    else if (b < 224) { int bb = b - 160; src = fom;  dst = b1t + 512 * 512; R = 512;  C = 512; r0 = (bb >> 3) * 64; c0 = (bb & 7) * 64; }
    else              { int bb = b - 224; src = hid2; dst = h2t;             R = 1024; C = 512; r0 = (bb >> 3) * 64; c0 = (bb & 7) * 64; }
    const int ty = t >> 4, tx = t & 15;
    #pragma unroll
    for (int q = 0; q < 4; ++q) {
        float4 v = *(const float4*)&src[(r0 + ty + q * 16) * C + c0 + tx * 4];
        tile[ty + q * 16][tx * 4 + 0] = v.x;
        tile[ty + q * 16][tx * 4 + 1] = v.y;
        tile[ty + q * 16][tx * 4 + 2] = v.z;
        tile[ty + q * 16][tx * 4 + 3] = v.w;
    }
    __syncthreads();
    #pragma unroll
    for (int q = 0; q < 4; ++q) {
        int cl = ty + q * 16;
        ushort4 o;
        o.x = f2bf(tile[tx * 4 + 0][cl]);
        o.y = f2bf(tile[tx * 4 + 1][cl]);
        o.z = f2bf(tile[tx * 4 + 2][cl]);
        o.w = f2bf(tile[tx * 4 + 3][cl]);
        *(ushort4*)&dst[(c0 + cl) * R + r0 + tx * 4] = o;
    }
}

// ---------------------------------------------------------------------------
// GEMM1 (MFMA bf16): act = tanh(xb @ b1t^T + catBias), bf16 out
// 1-wave blocks, 32x32 tile, grid 32x24 = 768 blocks (3/CU).
// ---------------------------------------------------------------------------
__global__ __launch_bounds__(64) void k_gemm1(
    const ushort* __restrict__ xb, const ushort* __restrict__ b1t,
    const float* __restrict__ catBias, ushort* __restrict__ act)
{
    const int lane = threadIdx.x;
    const int n0 = blockIdx.x * 32;
    const int m0 = blockIdx.y * 32;
    const int lrow = lane & 15, lk = (lane >> 4) * 8;

    const ushort* pa0 = &xb[(m0 + lrow) * KD + lk];
    const ushort* pa1 = pa0 + 16 * KD;
    const ushort* pb0 = &b1t[(n0 + lrow) * KD + lk];
    const ushort* pb1 = pb0 + 16 * KD;

    f32x4 acc[2][2] = {};
    #pragma unroll 4
    for (int k0 = 0; k0 < KD; k0 += 32) {
        short8 a0 = *(const short8*)(pa0 + k0);
        short8 a1 = *(const short8*)(pa1 + k0);
        short8 b0 = *(const short8*)(pb0 + k0);
        short8 b1 = *(const short8*)(pb1 + k0);
        acc[0][0] = __builtin_amdgcn_mfma_f32_16x16x32_bf16(a0, b0, acc[0][0], 0, 0, 0);
        acc[0][1] = __builtin_amdgcn_mfma_f32_16x16x32_bf16(a0, b1, acc[0][1], 0, 0, 0);
        acc[1][0] = __builtin_amdgcn_mfma_f32_16x16x32_bf16(a1, b0, acc[1][0], 0, 0, 0);
        acc[1][1] = __builtin_amdgcn_mfma_f32_16x16x32_bf16(a1, b1, acc[1][1], 0, 0, 0);
    }
    const int crow = (lane >> 4) * 4, ccol = lane & 15;
    #pragma unroll
    for (int nf = 0; nf < 2; ++nf) {
        int col = n0 + nf * 16 + ccol;
        float cb = catBias[col];
        #pragma unroll
        for (int mf = 0; mf < 2; ++mf) {
            #pragma unroll
            for (int r = 0; r < 4; ++r) {
                int row = m0 + mf * 16 + crow + r;
                act[row * NC + col] = f2bf(fast_tanh(acc[mf][nf][r] + cb));
            }
        }
    }
}

// ---------------------------------------------------------------------------
// GEMM2 (MFMA bf16) + exp epilogue -> pw = EA | EM (f32). Same tiling.
// ---------------------------------------------------------------------------
__global__ __launch_bounds__(64) void k_gemm2(
    const ushort* __restrict__ act, const ushort* __restrict__ h2t,
    const float* __restrict__ hid2Bias, float* __restrict__ pw)
{
    const int lane = threadIdx.x;
    const int n0 = blockIdx.x * 32;
    const int m0 = blockIdx.y * 32;
    const bool top = (blockIdx.x < 16);
    const int koff = top ? 0 : 512;
    const int nc0  = top ? n0 : n0 - 512;
    const int lrow = lane & 15, lk = (lane >> 4) * 8;

    const ushort* pa0 = &act[(m0 + lrow) * NC + koff + lk];
    const ushort* pa1 = pa0 + 16 * NC;
    const ushort* pb0 = &h2t[(nc0 + lrow) * NC + koff + lk];
    const ushort* pb1 = pb0 + 16 * NC;

    f32x4 acc[2][2] = {};
    #pragma unroll 4
    for (int k0 = 0; k0 < KD; k0 += 32) {
        short8 a0 = *(const short8*)(pa0 + k0);
        short8 a1 = *(const short8*)(pa1 + k0);
        short8 b0 = *(const short8*)(pb0 + k0);
        short8 b1 = *(const short8*)(pb1 + k0);
        acc[0][0] = __builtin_amdgcn_mfma_f32_16x16x32_bf16(a0, b0, acc[0][0], 0, 0, 0);
        acc[0][1] = __builtin_amdgcn_mfma_f32_16x16x32_bf16(a0, b1, acc[0][1], 0, 0, 0);
        acc[1][0] = __builtin_amdgcn_mfma_f32_16x16x32_bf16(a1, b0, acc[1][0], 0, 0, 0);
        acc[1][1] = __builtin_amdgcn_mfma_f32_16x16x32_bf16(a1, b1, acc[1][1], 0, 0, 0);
    }
    const int crow = (lane >> 4) * 4, ccol = lane & 15;
    #pragma unroll
    for (int nf = 0; nf < 2; ++nf) {
        int col = n0 + nf * 16 + ccol;
        float hb = top ? hid2Bias[col] : 0.0f;
        #pragma unroll
        for (int mf = 0; mf < 2; ++mf) {
            #pragma unroll
            for (int r = 0; r < 4; ++r) {
                int row = m0 + mf * 16 + crow + r;
                pw[row * NC + col] = fast_exp2(RLN2_2 * (acc[mf][nf][r] + hb));
            }
        }
    }
}

// ---------------------------------------------------------------------------
// Pairwise: out[i][j] = (outBias + sum w) - 2*sum_h w[h]/(1 + EA[i,h]*EM[j,h])
// H-SPLIT: both waves of a block compute the FULL 16x16 tile; wave wv covers
// h in [wv*256, wv*256+256). Each lane: 2i x 2j micro -> LDS reads drop to
// 4 b128 / 16 evals (was 6 / 16). Wave-private staging (no main-loop
// barriers); 32-h chunks keep LDS at 10752 B. Combine via wl overlay at end.
// Grid 2304 (XCD-swz) x 2 waves = 18 waves/CU.
// ---------------------------------------------------------------------------
__global__ __launch_bounds__(128) void k_pair(
    const float* __restrict__ pw, const float* __restrict__ w,
    const float* __restrict__ outBias, float* __restrict__ out)
{
    __shared__ float Ea[2][16][34];
    __shared__ float Em[2][16][34];
    __shared__ float wl[512];

    const int t    = threadIdx.x;
    const int wv   = t >> 6, lane = t & 63;
    const int bid  = blockIdx.x;
    const int sw   = (bid & 7) * 288 + (bid >> 3);   // XCD swizzle (8 | 2304)
    const int it = sw / 48, jt = sw % 48;
    const int i0 = it * 16, j0 = jt * 16;
    const int hb0 = wv * 256;                        // this wave's h-base

    // w: each wave stages its own h-half; lsum over full 512 via butterfly
    *(float4*)&wl[hb0 + lane * 4] = *(const float4*)&w[hb0 + lane * 4];
    float4 wa = *(const float4*)&w[lane * 8];
    float4 wb = *(const float4*)&w[lane * 8 + 4];
    float lsum = (wa.x + wa.y) + (wa.z + wa.w) + (wb.x + wb.y) + (wb.z + wb.w);
    #pragma unroll
    for (int d = 1; d < 64; d <<= 1) lsum += __shfl_xor(lsum, d, 64);

    // staging geometry: 16 rows x 32 cols per array; 8 floats (2 f4) / lane
    const int sr = lane >> 2;            // 0..15
    const int sc = (lane & 3) * 8;       // 0..24
    const float* srcA = &pw[(i0 + sr) * NC + hb0 + sc];
    const float* srcM = &pw[(j0 + sr) * NC + 512 + hb0 + sc];

    // compute geometry: lane = (li, lj) 8x8; rows 2li,2li+1; cols 2lj,2lj+1
    const int li = lane >> 3, lj = lane & 7;

    float4 fa0 = *(const float4*)(srcA);
    float4 fa1 = *(const float4*)(srcA + 4);
    float4 fm0 = *(const float4*)(srcM);
    float4 fm1 = *(const float4*)(srcM + 4);

    // 8 accumulators: [slot 0/1][2x2 position]
    float a00[2] = {}, a01[2] = {}, a10[2] = {}, a11[2] = {};

    #pragma unroll 1
    for (int c = 0; c < 8; ++c) {                    // 8 chunks x 32 h
        const int hh = c * 32;
        // stage current chunk (wave-private; DS pipe in-order per wave)
        *(float4*)&Ea[wv][sr][sc]     = fa0;
        *(float4*)&Ea[wv][sr][sc + 4] = fa1;
        *(float4*)&Em[wv][sr][sc]     = fm0;
        *(float4*)&Em[wv][sr][sc + 4] = fm1;
        if (c < 7) {
            fa0 = *(const float4*)(srcA + hh + 32);
            fa1 = *(const float4*)(srcA + hh + 36);
            fm0 = *(const float4*)(srcM + hh + 32);
            fm1 = *(const float4*)(srcM + hh + 36);
        }
        #pragma unroll
        for (int hq = 0; hq < 8; ++hq) {
            float4 e0 = *(const float4*)&Ea[wv][2 * li    ][hq * 4];
            float4 e1 = *(const float4*)&Ea[wv][2 * li + 1][hq * 4];
            float4 f0 = *(const float4*)&Em[wv][2 * lj    ][hq * 4];
            float4 f1 = *(const float4*)&Em[wv][2 * lj + 1][hq * 4];
            float4 w4 = *(const float4*)&wl[hb0 + hh + hq * 4];  // broadcast
            #define QUAD(H, S)                                                   \
            {                                                                    \
                float d00 = fmaf(e0.H, f0.H, 1.f), d01 = fmaf(e0.H, f1.H, 1.f);  \
                float d10 = fmaf(e1.H, f0.H, 1.f), d11 = fmaf(e1.H, f1.H, 1.f);  \
                float P0 = d00 * d01, P1 = d10 * d11;                            \
                float R  = fast_rcp(P0 * P1);                                    \
                float rw = R * w4.H;                                             \
                float rw0 = rw * P1, rw1 = rw * P0;                              \
                a00[S] = fmaf(rw0, d01, a00[S]);                                 \
                a01[S] = fmaf(rw0, d00, a01[S]);                                 \
                a10[S] = fmaf(rw1, d11, a10[S]);                                 \
                a11[S] = fmaf(rw1, d10, a11[S]);                                 \
            }
            QUAD(x, 0) QUAD(y, 1) QUAD(z, 0) QUAD(w, 1)
            #undef QUAD
        }
    }

    const float s00 = a00[0] + a00[1];
    const float s01 = a01[0] + a01[1];
    const float s10 = a10[0] + a10[1];
    const float s11 = a11[0] + a11[1];

    // combine h-halves: wave1 -> wl overlay -> wave0 adds and writes out
    float* partial = wl;
    __syncthreads();
    if (wv == 1) {
        partial[lane * 4 + 0] = s00;
        partial[lane * 4 + 1] = s01;
        partial[lane * 4 + 2] = s10;
        partial[lane * 4 + 3] = s11;
    }
    __syncthreads();
    if (wv == 0) {
        const float base = lsum + outBias[0];
        const int gi = i0 + 2 * li, gj = j0 + 2 * lj;
        float2 o0, o1;
        o0.x = fmaf(-2.f, s00 + partial[lane * 4 + 0], base);
        o0.y = fmaf(-2.f, s01 + partial[lane * 4 + 1], base);
        o1.x = fmaf(-2.f, s10 + partial[lane * 4 + 2], base);
        o1.y = fmaf(-2.f, s11 + partial[lane * 4 + 3], base);
        *(float2*)&out[gi * TT + gj]       = o0;
        *(float2*)&out[(gi + 1) * TT + gj] = o1;
    }
}

extern "C" void kernel_launch(void* const* d_in, const int* in_sizes, int n_in,
                              void* d_out, int out_size, void* d_ws, size_t ws_size,
                              hipStream_t stream) {
    const float* x        = (const float*)d_in[0];
    const float* foh      = (const float*)d_in[1];
    const float* fom      = (const float*)d_in[2];
    const float* catBias  = (const float*)d_in[3];
    const float* hid2     = (const float*)d_in[4];
    const float* hid2Bias = (const float*)d_in[5];
    const float* outLayer = (const float*)d_in[6];
    const float* outBias  = (const float*)d_in[7];
    float* out = (float*)d_out;

    char* wsb = (char*)d_ws;
    float*  pw  = (float*)(wsb);                        // 768*1024*4
    ushort* act = (ushort*)(wsb + 3145728);             // 768*1024*2
    ushort* xb  = (ushort*)(wsb + 4718592);             // 768*512*2
    ushort* b1t = (ushort*)(wsb + 5505024);             // 1024*512*2
    ushort* h2t = (ushort*)(wsb + 6553600);             // 512*1024*2

    k_prep <<<dim3(352),    256, 0, stream>>>(x, foh, fom, hid2, xb, b1t, h2t);
    k_gemm1<<<dim3(32, 24),  64, 0, stream>>>(xb, b1t, catBias, act);
    k_gemm2<<<dim3(32, 24),  64, 0, stream>>>(act, h2t, hid2Bias, pw);
    k_pair <<<dim3(2304),   128, 0, stream>>>(pw, outLayer, outBias, out);
}

// Round 11
// 69.286 us; speedup vs baseline: 1.7469x; 1.0422x over previous
//
#include <hip/hip_runtime.h>

#define TT 768
#define KD 512
#define NC 1024
#define RLN2_2 2.8853900817779268f   // 2/ln(2)

typedef short short8 __attribute__((ext_vector_type(8)));
typedef float f32x4  __attribute__((ext_vector_type(4)));

__device__ __forceinline__ float fast_exp2(float x) {
#if __has_builtin(__builtin_amdgcn_exp2f)
    return __builtin_amdgcn_exp2f(x);
#else
    return exp2f(x);
#endif
}
__device__ __forceinline__ float fast_rcp(float x) {
#if __has_builtin(__builtin_amdgcn_rcpf)
    return __builtin_amdgcn_rcpf(x);
#else
    return 1.0f / x;
#endif
}
__device__ __forceinline__ float fast_tanh(float x) {
    float e = fast_exp2(x * RLN2_2);
    return fmaf(-2.0f, fast_rcp(e + 1.0f), 1.0f);
}
__device__ __forceinline__ ushort f2bf(float f) {   // RNE f32->bf16
    uint u = __float_as_uint(f);
    u += 0x7fff + ((u >> 16) & 1);
    return (ushort)(u >> 16);
}

// ---------------------------------------------------------------------------
// Prep: x->bf16; foh/fom -> [c][k] bf16; hid2 -> [n][k] bf16 (transposes)
// ---------------------------------------------------------------------------
__global__ __launch_bounds__(256) void k_prep(
    const float* __restrict__ x, const float* __restrict__ foh,
    const float* __restrict__ fom, const float* __restrict__ hid2,
    ushort* __restrict__ xb, ushort* __restrict__ b1t, ushort* __restrict__ h2t)
{
    const int b = blockIdx.x, t = threadIdx.x;
    if (b < 96) {
        int base = b * 4096 + t * 16;
        #pragma unroll
        for (int q = 0; q < 4; ++q) {
            float4 v = *(const float4*)&x[base + q * 4];
            ushort4 o; o.x = f2bf(v.x); o.y = f2bf(v.y); o.z = f2bf(v.z); o.w = f2bf(v.w);
            *(ushort4*)&xb[base + q * 4] = o;
        }
        return;
    }
    __shared__ float tile[64][65];
    const float* src; ushort* dst; int R, C, r0, c0;
    if (b < 160)      { int bb = b - 96;  src = foh;  dst = b1t;             R = 512;  C = 512; r0 = (bb >> 3) * 64; c0 = (bb & 7) * 64; }
    else if (b < 224) { int bb = b - 160; src = fom;  dst = b1t + 512 * 512; R = 512;  C = 512; r0 = (bb >> 3) * 64; c0 = (bb & 7) * 64; }
    else              { int bb = b - 224; src = hid2; dst = h2t;             R = 1024; C = 512; r0 = (bb >> 3) * 64; c0 = (bb & 7) * 64; }
    const int ty = t >> 4, tx = t & 15;
    #pragma unroll
    for (int q = 0; q < 4; ++q) {
        float4 v = *(const float4*)&src[(r0 + ty + q * 16) * C + c0 + tx * 4];
        tile[ty + q * 16][tx * 4 + 0] = v.x;
        tile[ty + q * 16][tx * 4 + 1] = v.y;
        tile[ty + q * 16][tx * 4 + 2] = v.z;
        tile[ty + q * 16][tx * 4 + 3] = v.w;
    }
    __syncthreads();
    #pragma unroll
    for (int q = 0; q < 4; ++q) {
        int cl = ty + q * 16;
        ushort4 o;
        o.x = f2bf(tile[tx * 4 + 0][cl]);
        o.y = f2bf(tile[tx * 4 + 1][cl]);
        o.z = f2bf(tile[tx * 4 + 2][cl]);
        o.w = f2bf(tile[tx * 4 + 3][cl]);
        *(ushort4*)&dst[(c0 + cl) * R + r0 + tx * 4] = o;
    }
}

// ---------------------------------------------------------------------------
// GEMM1 (MFMA bf16): act = tanh(xb @ b1t^T + catBias), bf16 out
// 1-wave blocks, 16x32 tile (1x2 16x16x32 frags), grid 32x48 = 1536 blocks
// = 6 waves/CU (was 3) for latency hiding.
// ---------------------------------------------------------------------------
__global__ __launch_bounds__(64) void k_gemm1(
    const ushort* __restrict__ xb, const ushort* __restrict__ b1t,
    const float* __restrict__ catBias, ushort* __restrict__ act)
{
    const int lane = threadIdx.x;
    const int n0 = blockIdx.x * 32;
    const int m0 = blockIdx.y * 16;
    const int lrow = lane & 15, lk = (lane >> 4) * 8;

    const ushort* pa  = &xb[(m0 + lrow) * KD + lk];
    const ushort* pb0 = &b1t[(n0 + lrow) * KD + lk];
    const ushort* pb1 = pb0 + 16 * KD;

    f32x4 acc0 = {}, acc1 = {};
    #pragma unroll 8
    for (int k0 = 0; k0 < KD; k0 += 32) {
        short8 a  = *(const short8*)(pa  + k0);
        short8 b0 = *(const short8*)(pb0 + k0);
        short8 b1 = *(const short8*)(pb1 + k0);
        acc0 = __builtin_amdgcn_mfma_f32_16x16x32_bf16(a, b0, acc0, 0, 0, 0);
        acc1 = __builtin_amdgcn_mfma_f32_16x16x32_bf16(a, b1, acc1, 0, 0, 0);
    }
    const int crow = (lane >> 4) * 4, ccol = lane & 15;
    const float cb0 = catBias[n0 + ccol];
    const float cb1 = catBias[n0 + 16 + ccol];
    #pragma unroll
    for (int r = 0; r < 4; ++r) {
        int row = m0 + crow + r;
        act[row * NC + n0 + ccol]      = f2bf(fast_tanh(acc0[r] + cb0));
        act[row * NC + n0 + 16 + ccol] = f2bf(fast_tanh(acc1[r] + cb1));
    }
}

// ---------------------------------------------------------------------------
// GEMM2 (MFMA bf16) + exp epilogue -> pw = EA | EM (f32). Same 16x32 tiling.
// ---------------------------------------------------------------------------
__global__ __launch_bounds__(64) void k_gemm2(
    const ushort* __restrict__ act, const ushort* __restrict__ h2t,
    const float* __restrict__ hid2Bias, float* __restrict__ pw)
{
    const int lane = threadIdx.x;
    const int n0 = blockIdx.x * 32;
    const int m0 = blockIdx.y * 16;
    const bool top = (blockIdx.x < 16);
    const int koff = top ? 0 : 512;
    const int nc0  = top ? n0 : n0 - 512;
    const int lrow = lane & 15, lk = (lane >> 4) * 8;

    const ushort* pa  = &act[(m0 + lrow) * NC + koff + lk];
    const ushort* pb0 = &h2t[(nc0 + lrow) * NC + koff + lk];
    const ushort* pb1 = pb0 + 16 * NC;

    f32x4 acc0 = {}, acc1 = {};
    #pragma unroll 8
    for (int k0 = 0; k0 < KD; k0 += 32) {
        short8 a  = *(const short8*)(pa  + k0);
        short8 b0 = *(const short8*)(pb0 + k0);
        short8 b1 = *(const short8*)(pb1 + k0);
        acc0 = __builtin_amdgcn_mfma_f32_16x16x32_bf16(a, b0, acc0, 0, 0, 0);
        acc1 = __builtin_amdgcn_mfma_f32_16x16x32_bf16(a, b1, acc1, 0, 0, 0);
    }
    const int crow = (lane >> 4) * 4, ccol = lane & 15;
    const float hb0 = top ? hid2Bias[n0 + ccol]      : 0.0f;
    const float hb1 = top ? hid2Bias[n0 + 16 + ccol] : 0.0f;
    #pragma unroll
    for (int r = 0; r < 4; ++r) {
        int row = m0 + crow + r;
        pw[row * NC + n0 + ccol]      = fast_exp2(RLN2_2 * (acc0[r] + hb0));
        pw[row * NC + n0 + 16 + ccol] = fast_exp2(RLN2_2 * (acc1[r] + hb1));
    }
}

// ---------------------------------------------------------------------------
// Pairwise: out[i][j] = (outBias + sum w) - 2*sum_h w[h]/(1 + EA[i,h]*EM[j,h])
// 4-WAY H-SPLIT: 256-thr block (4 waves); wave wv covers h in [wv*128,+128).
// All 4 waves compute the full 16x16 tile; 2i x 2j micro per lane; combine
// via LDS overlay. Wave-private staging (no main-loop barriers), 16-h chunks.
// LDS 11264 B -> 8 blocks/CU = 32 waves/CU (hardware max).
// Grid 2304 (XCD-swizzled).
// ---------------------------------------------------------------------------
__global__ __launch_bounds__(256) void k_pair(
    const float* __restrict__ pw, const float* __restrict__ w,
    const float* __restrict__ outBias, float* __restrict__ out)
{
    __shared__ float Ea[4][16][18];
    __shared__ float Em[4][16][18];
    __shared__ float wl[512];

    const int t    = threadIdx.x;
    const int wv   = t >> 6, lane = t & 63;
    const int bid  = blockIdx.x;
    const int sw   = (bid & 7) * 288 + (bid >> 3);   // XCD swizzle (8 | 2304)
    const int it = sw / 48, jt = sw % 48;
    const int i0 = it * 16, j0 = jt * 16;
    const int hb0 = wv * 128;                        // this wave's h-base

    // w: each wave stages its own h-quarter (reads only its own quarter,
    // ordered behind its own writes). lsum over full 512 via global+butterfly.
    *(float2*)&wl[hb0 + lane * 2] = *(const float2*)&w[hb0 + lane * 2];
    float4 wa = *(const float4*)&w[lane * 8];
    float4 wb = *(const float4*)&w[lane * 8 + 4];
    float lsum = (wa.x + wa.y) + (wa.z + wa.w) + (wb.x + wb.y) + (wb.z + wb.w);
    #pragma unroll
    for (int d = 1; d < 64; d <<= 1) lsum += __shfl_xor(lsum, d, 64);

    // staging geometry: 16 rows x 16 cols per chunk; 1 float4 / lane / array
    const int sr = lane >> 2;            // 0..15
    const int sc = (lane & 3) * 4;       // 0..12
    const float* srcA = &pw[(i0 + sr) * NC + hb0 + sc];
    const float* srcM = &pw[(j0 + sr) * NC + 512 + hb0 + sc];

    // compute geometry: lane = (li, lj) 8x8; rows 2li,2li+1; cols 2lj,2lj+1
    const int li = lane >> 3, lj = lane & 7;

    float4 fa = *(const float4*)(srcA);
    float4 fm = *(const float4*)(srcM);

    float a00[2] = {}, a01[2] = {}, a10[2] = {}, a11[2] = {};

    #pragma unroll 1
    for (int c = 0; c < 8; ++c) {                    // 8 chunks x 16 h
        const int hh = c * 16;
        *(float4*)&Ea[wv][sr][sc] = fa;              // wave-private; in-order
        *(float4*)&Em[wv][sr][sc] = fm;
        if (c < 7) {
            fa = *(const float4*)(srcA + hh + 16);
            fm = *(const float4*)(srcM + hh + 16);
        }
        #pragma unroll
        for (int hq = 0; hq < 4; ++hq) {
            float4 e0 = *(const float4*)&Ea[wv][2 * li    ][hq * 4];
            float4 e1 = *(const float4*)&Ea[wv][2 * li + 1][hq * 4];
            float4 f0 = *(const float4*)&Em[wv][2 * lj    ][hq * 4];
            float4 f1 = *(const float4*)&Em[wv][2 * lj + 1][hq * 4];
            float4 w4 = *(const float4*)&wl[hb0 + hh + hq * 4];  // broadcast
            #define QUAD(H, S)                                                   \
            {                                                                    \
                float d00 = fmaf(e0.H, f0.H, 1.f), d01 = fmaf(e0.H, f1.H, 1.f);  \
                float d10 = fmaf(e1.H, f0.H, 1.f), d11 = fmaf(e1.H, f1.H, 1.f);  \
                float P0 = d00 * d01, P1 = d10 * d11;                            \
                float R  = fast_rcp(P0 * P1);                                    \
                float rw = R * w4.H;                                             \
                float rw0 = rw * P1, rw1 = rw * P0;                              \
                a00[S] = fmaf(rw0, d01, a00[S]);                                 \
                a01[S] = fmaf(rw0, d00, a01[S]);                                 \
                a10[S] = fmaf(rw1, d11, a10[S]);                                 \
                a11[S] = fmaf(rw1, d10, a11[S]);                                 \
            }
            QUAD(x, 0) QUAD(y, 1) QUAD(z, 0) QUAD(w, 1)
            #undef QUAD
        }
    }

    const float s00 = a00[0] + a00[1];
    const float s01 = a01[0] + a01[1];
    const float s10 = a10[0] + a10[1];
    const float s11 = a11[0] + a11[1];

    // combine 4 h-quarters: waves 1..3 park partials in LDS (overlay on Ea,
    // 768 floats <= 2176), wave 0 sums and writes out.
    float* partial = (float*)Ea;
    __syncthreads();
    if (wv >= 1) {
        float* p = partial + (wv - 1) * 256 + lane * 4;
        p[0] = s00; p[1] = s01; p[2] = s10; p[3] = s11;
    }
    __syncthreads();
    if (wv == 0) {
        const float base = lsum + outBias[0];
        float t00 = s00, t01 = s01, t10 = s10, t11 = s11;
        #pragma unroll
        for (int q = 0; q < 3; ++q) {
            const float* p = partial + q * 256 + lane * 4;
            t00 += p[0]; t01 += p[1]; t10 += p[2]; t11 += p[3];
        }
        const int gi = i0 + 2 * li, gj = j0 + 2 * lj;
        float2 o0, o1;
        o0.x = fmaf(-2.f, t00, base);
        o0.y = fmaf(-2.f, t01, base);
        o1.x = fmaf(-2.f, t10, base);
        o1.y = fmaf(-2.f, t11, base);
        *(float2*)&out[gi * TT + gj]       = o0;
        *(float2*)&out[(gi + 1) * TT + gj] = o1;
    }
}

extern "C" void kernel_launch(void* const* d_in, const int* in_sizes, int n_in,
                              void* d_out, int out_size, void* d_ws, size_t ws_size,
                              hipStream_t stream) {
    const float* x        = (const float*)d_in[0];
    const float* foh      = (const float*)d_in[1];
    const float* fom      = (const float*)d_in[2];
    const float* catBias  = (const float*)d_in[3];
    const float* hid2     = (const float*)d_in[4];
    const float* hid2Bias = (const float*)d_in[5];
    const float* outLayer = (const float*)d_in[6];
    const float* outBias  = (const float*)d_in[7];
    float* out = (float*)d_out;

    char* wsb = (char*)d_ws;
    float*  pw  = (float*)(wsb);                        // 768*1024*4
    ushort* act = (ushort*)(wsb + 3145728);             // 768*1024*2
    ushort* xb  = (ushort*)(wsb + 4718592);             // 768*512*2
    ushort* b1t = (ushort*)(wsb + 5505024);             // 1024*512*2
    ushort* h2t = (ushort*)(wsb + 6553600);             // 512*1024*2

    k_prep <<<dim3(352),    256, 0, stream>>>(x, foh, fom, hid2, xb, b1t, h2t);
    k_gemm1<<<dim3(32, 48),  64, 0, stream>>>(xb, b1t, catBias, act);
    k_gemm2<<<dim3(32, 48),  64, 0, stream>>>(act, h2t, hid2Bias, pw);
    k_pair <<<dim3(2304),   256, 0, stream>>>(pw, outLayer, outBias, out);
}

// Round 12
// 63.875 us; speedup vs baseline: 1.8949x; 1.0847x over previous
//
#include <hip/hip_runtime.h>

#define TT 768
#define KD 512
#define NC 1024
#define RLN2_2 2.8853900817779268f   // 2/ln(2)

typedef short short8 __attribute__((ext_vector_type(8)));
typedef float f32x4  __attribute__((ext_vector_type(4)));
typedef float f32x2  __attribute__((ext_vector_type(2)));

__device__ __forceinline__ float fast_exp2(float x) {
#if __has_builtin(__builtin_amdgcn_exp2f)
    return __builtin_amdgcn_exp2f(x);
#else
    return exp2f(x);
#endif
}
__device__ __forceinline__ float fast_rcp(float x) {
#if __has_builtin(__builtin_amdgcn_rcpf)
    return __builtin_amdgcn_rcpf(x);
#else
    return 1.0f / x;
#endif
}
__device__ __forceinline__ float fast_tanh(float x) {
    float e = fast_exp2(x * RLN2_2);
    return fmaf(-2.0f, fast_rcp(e + 1.0f), 1.0f);
}
__device__ __forceinline__ ushort f2bf(float f) {   // RNE f32->bf16
    uint u = __float_as_uint(f);
    u += 0x7fff + ((u >> 16) & 1);
    return (ushort)(u >> 16);
}

// ---------------------------------------------------------------------------
// Prep: x->bf16; foh/fom -> [c][k] bf16; hid2 -> [n][k] bf16 (transposes)
// ---------------------------------------------------------------------------
__global__ __launch_bounds__(256) void k_prep(
    const float* __restrict__ x, const float* __restrict__ foh,
    const float* __restrict__ fom, const float* __restrict__ hid2,
    ushort* __restrict__ xb, ushort* __restrict__ b1t, ushort* __restrict__ h2t)
{
    const int b = blockIdx.x, t = threadIdx.x;
    if (b < 96) {
        int base = b * 4096 + t * 16;
        #pragma unroll
        for (int q = 0; q < 4; ++q) {
            float4 v = *(const float4*)&x[base + q * 4];
            ushort4 o; o.x = f2bf(v.x); o.y = f2bf(v.y); o.z = f2bf(v.z); o.w = f2bf(v.w);
            *(ushort4*)&xb[base + q * 4] = o;
        }
        return;
    }
    __shared__ float tile[64][65];
    const float* src; ushort* dst; int R, C, r0, c0;
    if (b < 160)      { int bb = b - 96;  src = foh;  dst = b1t;             R = 512;  C = 512; r0 = (bb >> 3) * 64; c0 = (bb & 7) * 64; }
    else if (b < 224) { int bb = b - 160; src = fom;  dst = b1t + 512 * 512; R = 512;  C = 512; r0 = (bb >> 3) * 64; c0 = (bb & 7) * 64; }
    else              { int bb = b - 224; src = hid2; dst = h2t;             R = 1024; C = 512; r0 = (bb >> 3) * 64; c0 = (bb & 7) * 64; }
    const int ty = t >> 4, tx = t & 15;
    #pragma unroll
    for (int q = 0; q < 4; ++q) {
        float4 v = *(const float4*)&src[(r0 + ty + q * 16) * C + c0 + tx * 4];
        tile[ty + q * 16][tx * 4 + 0] = v.x;
        tile[ty + q * 16][tx * 4 + 1] = v.y;
        tile[ty + q * 16][tx * 4 + 2] = v.z;
        tile[ty + q * 16][tx * 4 + 3] = v.w;
    }
    __syncthreads();
    #pragma unroll
    for (int q = 0; q < 4; ++q) {
        int cl = ty + q * 16;
        ushort4 o;
        o.x = f2bf(tile[tx * 4 + 0][cl]);
        o.y = f2bf(tile[tx * 4 + 1][cl]);
        o.z = f2bf(tile[tx * 4 + 2][cl]);
        o.w = f2bf(tile[tx * 4 + 3][cl]);
        *(ushort4*)&dst[(c0 + cl) * R + r0 + tx * 4] = o;
    }
}

// ---------------------------------------------------------------------------
// GEMM1 (MFMA bf16): act = tanh(xb @ b1t^T + catBias), bf16 out
// 1-wave blocks, 32x32 tile, grid 32x24 = 768 blocks (3/CU). [r10 version]
// ---------------------------------------------------------------------------
__global__ __launch_bounds__(64) void k_gemm1(
    const ushort* __restrict__ xb, const ushort* __restrict__ b1t,
    const float* __restrict__ catBias, ushort* __restrict__ act)
{
    const int lane = threadIdx.x;
    const int n0 = blockIdx.x * 32;
    const int m0 = blockIdx.y * 32;
    const int lrow = lane & 15, lk = (lane >> 4) * 8;

    const ushort* pa0 = &xb[(m0 + lrow) * KD + lk];
    const ushort* pa1 = pa0 + 16 * KD;
    const ushort* pb0 = &b1t[(n0 + lrow) * KD + lk];
    const ushort* pb1 = pb0 + 16 * KD;

    f32x4 acc[2][2] = {};
    #pragma unroll 4
    for (int k0 = 0; k0 < KD; k0 += 32) {
        short8 a0 = *(const short8*)(pa0 + k0);
        short8 a1 = *(const short8*)(pa1 + k0);
        short8 b0 = *(const short8*)(pb0 + k0);
        short8 b1 = *(const short8*)(pb1 + k0);
        acc[0][0] = __builtin_amdgcn_mfma_f32_16x16x32_bf16(a0, b0, acc[0][0], 0, 0, 0);
        acc[0][1] = __builtin_amdgcn_mfma_f32_16x16x32_bf16(a0, b1, acc[0][1], 0, 0, 0);
        acc[1][0] = __builtin_amdgcn_mfma_f32_16x16x32_bf16(a1, b0, acc[1][0], 0, 0, 0);
        acc[1][1] = __builtin_amdgcn_mfma_f32_16x16x32_bf16(a1, b1, acc[1][1], 0, 0, 0);
    }
    const int crow = (lane >> 4) * 4, ccol = lane & 15;
    #pragma unroll
    for (int nf = 0; nf < 2; ++nf) {
        int col = n0 + nf * 16 + ccol;
        float cb = catBias[col];
        #pragma unroll
        for (int mf = 0; mf < 2; ++mf) {
            #pragma unroll
            for (int r = 0; r < 4; ++r) {
                int row = m0 + mf * 16 + crow + r;
                act[row * NC + col] = f2bf(fast_tanh(acc[mf][nf][r] + cb));
            }
        }
    }
}

// ---------------------------------------------------------------------------
// GEMM2 (MFMA bf16) + exp epilogue -> pw = EA | EM (f32). [r10 version]
// ---------------------------------------------------------------------------
__global__ __launch_bounds__(64) void k_gemm2(
    const ushort* __restrict__ act, const ushort* __restrict__ h2t,
    const float* __restrict__ hid2Bias, float* __restrict__ pw)
{
    const int lane = threadIdx.x;
    const int n0 = blockIdx.x * 32;
    const int m0 = blockIdx.y * 32;
    const bool top = (blockIdx.x < 16);
    const int koff = top ? 0 : 512;
    const int nc0  = top ? n0 : n0 - 512;
    const int lrow = lane & 15, lk = (lane >> 4) * 8;

    const ushort* pa0 = &act[(m0 + lrow) * NC + koff + lk];
    const ushort* pa1 = pa0 + 16 * NC;
    const ushort* pb0 = &h2t[(nc0 + lrow) * NC + koff + lk];
    const ushort* pb1 = pb0 + 16 * NC;

    f32x4 acc[2][2] = {};
    #pragma unroll 4
    for (int k0 = 0; k0 < KD; k0 += 32) {
        short8 a0 = *(const short8*)(pa0 + k0);
        short8 a1 = *(const short8*)(pa1 + k0);
        short8 b0 = *(const short8*)(pb0 + k0);
        short8 b1 = *(const short8*)(pb1 + k0);
        acc[0][0] = __builtin_amdgcn_mfma_f32_16x16x32_bf16(a0, b0, acc[0][0], 0, 0, 0);
        acc[0][1] = __builtin_amdgcn_mfma_f32_16x16x32_bf16(a0, b1, acc[0][1], 0, 0, 0);
        acc[1][0] = __builtin_amdgcn_mfma_f32_16x16x32_bf16(a1, b0, acc[1][0], 0, 0, 0);
        acc[1][1] = __builtin_amdgcn_mfma_f32_16x16x32_bf16(a1, b1, acc[1][1], 0, 0, 0);
    }
    const int crow = (lane >> 4) * 4, ccol = lane & 15;
    #pragma unroll
    for (int nf = 0; nf < 2; ++nf) {
        int col = n0 + nf * 16 + ccol;
        float hb = top ? hid2Bias[col] : 0.0f;
        #pragma unroll
        for (int mf = 0; mf < 2; ++mf) {
            #pragma unroll
            for (int r = 0; r < 4; ++r) {
                int row = m0 + mf * 16 + crow + r;
                pw[row * NC + col] = fast_exp2(RLN2_2 * (acc[mf][nf][r] + hb));
            }
        }
    }
}

// ---------------------------------------------------------------------------
// Pairwise: out[i][j] = (outBias + sum w) - 2*sum_h w[h]/(1 + EA[i,h]*EM[j,h])
// 32x16 (i x j) tile / 4-wave block; wave wv covers h in [wv*128,+128).
// Micro 4i x 2j per lane. PACKED f32x2 math (v_pk_fma targets): 8 packed
// issues + 1 rcp per 4 evals. w in per-chunk registers (scalar loads, not
// LDS, not per-h). Wave-private staging, no main-loop barriers, 16-h chunks.
// Grid 24x48=1152 (XCD-swz, 8|1152) x 4 waves = 18 waves/CU. LDS 13824 B.
// ---------------------------------------------------------------------------
__global__ __launch_bounds__(256) void k_pair(
    const float* __restrict__ pw, const float* __restrict__ w,
    const float* __restrict__ outBias, float* __restrict__ out)
{
    __shared__ float Ea[4][32][18];
    __shared__ float Em[4][16][18];

    const int t    = threadIdx.x;
    const int wv   = t >> 6, lane = t & 63;
    const int bid  = blockIdx.x;
    const int sw   = (bid & 7) * 144 + (bid >> 3);   // XCD swizzle (8 | 1152)
    const int it = sw / 48, jt = sw % 48;            // 24 x 48 tiles
    const int i0 = it * 32, j0 = jt * 16;
    const int hb0 = wv * 128;                        // this wave's h-quarter

    // lsum over full 512 via global reads + butterfly
    float4 wa = *(const float4*)&w[lane * 8];
    float4 wb = *(const float4*)&w[lane * 8 + 4];
    float lsum = (wa.x + wa.y) + (wa.z + wa.w) + (wb.x + wb.y) + (wb.z + wb.w);
    #pragma unroll
    for (int d = 1; d < 64; d <<= 1) lsum += __shfl_xor(lsum, d, 64);

    // staging geometry (per-chunk: Ea 32x16, Em 16x16)
    const int sra = lane >> 1;            // 0..31
    const int sca = (lane & 1) * 8;       // 0 or 8 (2 float4 each)
    const int srm = lane >> 2;            // 0..15
    const int scm = (lane & 3) * 4;       // 1 float4
    const float* srcA = &pw[(i0 + sra) * NC + hb0 + sca];
    const float* srcM = &pw[(j0 + srm) * NC + 512 + hb0 + scm];

    // compute geometry: lane = (li, lj) 8x8; rows 4li..4li+3, cols 2lj,2lj+1
    const int li = lane >> 3, lj = lane & 7;

    float4 fa0 = *(const float4*)(srcA);
    float4 fa1 = *(const float4*)(srcA + 4);
    float4 fm  = *(const float4*)(srcM);

    // w chunk registers (uniform address -> scalar loads, once per chunk)
    const float* wp = &w[hb0];
    float4 wch[4], wnx[4];
    #pragma unroll
    for (int q = 0; q < 4; ++q) wch[q] = *(const float4*)(wp + q * 4);

    const f32x2 one2 = {1.0f, 1.0f};
    f32x2 acc0[2] = {}, acc1[2] = {}, acc2[2] = {}, acc3[2] = {};

    #pragma unroll 1
    for (int c = 0; c < 8; ++c) {                    // 8 chunks x 16 h
        const int hh = c * 16;
        // stage (wave-private; DS pipe in-order per wave)
        *(float4*)&Ea[wv][sra][sca]     = fa0;
        *(float4*)&Ea[wv][sra][sca + 4] = fa1;
        *(float4*)&Em[wv][srm][scm]     = fm;
        if (c < 7) {
            fa0 = *(const float4*)(srcA + hh + 16);
            fa1 = *(const float4*)(srcA + hh + 20);
            fm  = *(const float4*)(srcM + hh + 16);
            #pragma unroll
            for (int q = 0; q < 4; ++q) wnx[q] = *(const float4*)(wp + hh + 16 + q * 4);
        }
        #pragma unroll
        for (int hq = 0; hq < 4; ++hq) {
            float4 e0 = *(const float4*)&Ea[wv][4 * li + 0][hq * 4];
            float4 e1 = *(const float4*)&Ea[wv][4 * li + 1][hq * 4];
            float4 e2 = *(const float4*)&Ea[wv][4 * li + 2][hq * 4];
            float4 e3 = *(const float4*)&Ea[wv][4 * li + 3][hq * 4];
            float4 f0 = *(const float4*)&Em[wv][2 * lj    ][hq * 4];
            float4 f1 = *(const float4*)&Em[wv][2 * lj + 1][hq * 4];
            float4 w4 = wch[hq];
            #define PKQUAD(DA, DB, WH, ACCA, ACCB)                           \
            {                                                                \
                f32x2 Q  = DA * DB;                                          \
                float pr = Q.x * Q.y;                                        \
                float R  = fast_rcp(pr);                                     \
                float RW = R * (WH);                                         \
                f32x2 T  = (f32x2){Q.y, Q.x} * RW;                           \
                ACCA = __builtin_elementwise_fma(T, DB, ACCA);               \
                ACCB = __builtin_elementwise_fma(T, DA, ACCB);               \
            }
            #define HSTEP(H, S)                                                        \
            {                                                                          \
                f32x2 F  = {f0.H, f1.H};                                               \
                f32x2 D0 = __builtin_elementwise_fma((f32x2){e0.H, e0.H}, F, one2);    \
                f32x2 D1 = __builtin_elementwise_fma((f32x2){e1.H, e1.H}, F, one2);    \
                f32x2 D2 = __builtin_elementwise_fma((f32x2){e2.H, e2.H}, F, one2);    \
                f32x2 D3 = __builtin_elementwise_fma((f32x2){e3.H, e3.H}, F, one2);    \
                PKQUAD(D0, D1, w4.H, acc0[S], acc1[S])                                 \
                PKQUAD(D2, D3, w4.H, acc2[S], acc3[S])                                 \
            }
            HSTEP(x, 0) HSTEP(y, 1) HSTEP(z, 0) HSTEP(w, 1)
            #undef HSTEP
            #undef PKQUAD
        }
        if (c < 7) {
            #pragma unroll
            for (int q = 0; q < 4; ++q) wch[q] = wnx[q];
        }
    }

    f32x2 s0 = acc0[0] + acc0[1];
    f32x2 s1 = acc1[0] + acc1[1];
    f32x2 s2 = acc2[0] + acc2[1];
    f32x2 s3 = acc3[0] + acc3[1];

    // combine 4 h-quarters: waves 1..3 park 8 partials each in LDS overlay
    // on Ea (1536 floats <= 2304), wave 0 sums and writes out.
    float* partial = (float*)Ea;
    __syncthreads();
    if (wv >= 1) {
        float* p = partial + (wv - 1) * 512 + lane * 8;
        p[0] = s0.x; p[1] = s0.y; p[2] = s1.x; p[3] = s1.y;
        p[4] = s2.x; p[5] = s2.y; p[6] = s3.x; p[7] = s3.y;
    }
    __syncthreads();
    if (wv == 0) {
        const float base = lsum + outBias[0];
        float tt[8] = {s0.x, s0.y, s1.x, s1.y, s2.x, s2.y, s3.x, s3.y};
        #pragma unroll
        for (int q = 0; q < 3; ++q) {
            const float* p = partial + q * 512 + lane * 8;
            #pragma unroll
            for (int k = 0; k < 8; ++k) tt[k] += p[k];
        }
        const int gj = j0 + 2 * lj;
        #pragma unroll
        for (int r = 0; r < 4; ++r) {
            const int gi = i0 + 4 * li + r;
            float2 o;
            o.x = fmaf(-2.f, tt[2 * r],     base);
            o.y = fmaf(-2.f, tt[2 * r + 1], base);
            *(float2*)&out[gi * TT + gj] = o;
        }
    }
}

extern "C" void kernel_launch(void* const* d_in, const int* in_sizes, int n_in,
                              void* d_out, int out_size, void* d_ws, size_t ws_size,
                              hipStream_t stream) {
    const float* x        = (const float*)d_in[0];
    const float* foh      = (const float*)d_in[1];
    const float* fom      = (const float*)d_in[2];
    const float* catBias  = (const float*)d_in[3];
    const float* hid2     = (const float*)d_in[4];
    const float* hid2Bias = (const float*)d_in[5];
    const float* outLayer = (const float*)d_in[6];
    const float* outBias  = (const float*)d_in[7];
    float* out = (float*)d_out;

    char* wsb = (char*)d_ws;
    float*  pw  = (float*)(wsb);                        // 768*1024*4
    ushort* act = (ushort*)(wsb + 3145728);             // 768*1024*2
    ushort* xb  = (ushort*)(wsb + 4718592);             // 768*512*2
    ushort* b1t = (ushort*)(wsb + 5505024);             // 1024*512*2
    ushort* h2t = (ushort*)(wsb + 6553600);             // 512*1024*2

    k_prep <<<dim3(352),    256, 0, stream>>>(x, foh, fom, hid2, xb, b1t, h2t);
    k_gemm1<<<dim3(32, 24),  64, 0, stream>>>(xb, b1t, catBias, act);
    k_gemm2<<<dim3(32, 24),  64, 0, stream>>>(act, h2t, hid2Bias, pw);
    k_pair <<<dim3(1152),   256, 0, stream>>>(pw, outLayer, outBias, out);
}